// Round 2
// baseline (1166.624 us; speedup 1.0000x reference)
//
#include <hip/hip_runtime.h>

typedef unsigned short u16;
typedef unsigned int u32;
typedef __attribute__((ext_vector_type(8))) short short8;
typedef __attribute__((ext_vector_type(4))) float f32x4;

#define N_NODES 10000
#define N_EDGES 100000
#define C_CH 64
#define S_SPH 16
#define NB_R 8
#define HID_D 64
#define NE_EL 10
#define G_GR 64
#define L_LAY 2
#define N_HEADS 1
#define RCUT 5.0f
#define INV_AVG (1.0f/16.0f)

__device__ __forceinline__ u16 f2bf(float f) {
  u32 u = __float_as_uint(f);
  u32 r = (u + 0x7FFFu + ((u >> 16) & 1u)) >> 16;
  return (u16)r;
}

__global__ void k_zero_out(float* out) {
  if (threadIdx.x < G_GR) out[threadIdx.x] = 0.0f;
}

__global__ void k_node_init(const float* __restrict__ attrs, const float* __restrict__ ae,
                            const int* __restrict__ batch, const int* __restrict__ head,
                            int* __restrict__ species, float* __restrict__ out) {
  int n = blockIdx.x * 256 + threadIdx.x;
  if (n >= N_NODES) return;
  int sp = 0;
#pragma unroll
  for (int e = 0; e < NE_EL; ++e)
    if (attrs[n * NE_EL + e] > 0.5f) sp = e;
  species[n] = sp;
  int b = batch[n];
  int h = head[b];
  atomicAdd(&out[b], ae[h * NE_EL + sp]);
}

__global__ void k_embed(const int* __restrict__ species, const float* __restrict__ Wemb,
                        float* __restrict__ feats) {
  int idx = blockIdx.x * 256 + threadIdx.x;
  if (idx >= N_NODES * C_CH) return;
  feats[idx] = Wemb[species[idx >> 6] * C_CH + (idx & 63)];
}

__global__ void k_geom(const float* __restrict__ pos, const float* __restrict__ shifts,
                       const int* __restrict__ ei, float* __restrict__ Y, float* __restrict__ rad) {
  int e = blockIdx.x * 256 + threadIdx.x;
  if (e >= N_EDGES) return;
  int s = ei[e], r = ei[N_EDGES + e];
  float dx = pos[r * 3 + 0] - pos[s * 3 + 0] + shifts[e * 3 + 0];
  float dy = pos[r * 3 + 1] - pos[s * 3 + 1] + shifts[e * 3 + 1];
  float dz = pos[r * 3 + 2] - pos[s * 3 + 2] + shifts[e * 3 + 2];
  float rr = sqrtf(dx * dx + dy * dy + dz * dz);
  rr = fmaxf(rr, 1e-12f);
  float inv = 1.0f / rr;
  float x = dx * inv, y = dy * inv, z = dz * inv;
  float xx = x * x, yy = y * y, zz = z * z;
  const float s3 = 1.73205080757f, s5 = 2.2360679775f, s15 = 3.87298334621f;
  const float c1 = 2.09165006634f, c2 = 10.2469507659f, c3 = 1.62018517461f;
  const float c4 = 1.32287565553f, c5 = 5.12347538298f;
  float4* Yo = (float4*)(Y + (size_t)e * 16);
  Yo[0] = make_float4(1.0f, s3 * x, s3 * y, s3 * z);
  Yo[1] = make_float4(s15 * x * y, s15 * y * z, 0.5f * s5 * (3.0f * zz - 1.0f), s15 * x * z);
  Yo[2] = make_float4(0.5f * s15 * (xx - yy), c1 * y * (3.0f * xx - yy), c2 * x * y * z,
                      c3 * y * (5.0f * zz - 1.0f));
  Yo[3] = make_float4(c4 * z * (5.0f * zz - 3.0f), c3 * x * (5.0f * zz - 1.0f),
                      c5 * z * (xx - yy), c1 * x * (xx - 3.0f * yy));
  float t = rr * (1.0f / RCUT);
  float t2 = t * t;
  float t6 = t2 * t2 * t2;
  float fcut = 1.0f - 28.0f * t6 + 48.0f * t6 * t - 21.0f * t6 * t2;
  if (rr >= RCUT) fcut = 0.0f;
  float pref = 0.63245553203f * inv * fcut;
  float arg = 3.14159265359f * rr * (1.0f / RCUT);
  float sa, ca;
  __sincosf(arg, &sa, &ca);
  float twoc = 2.0f * ca;
  float sprev = 0.0f, scur = sa;
  float rv[8];
#pragma unroll
  for (int n = 0; n < 8; ++n) {
    rv[n] = pref * scur;
    float snext = twoc * scur - sprev;
    sprev = scur;
    scur = snext;
  }
  float4* Ro = (float4*)(rad + (size_t)e * 8);
  Ro[0] = make_float4(rv[0], rv[1], rv[2], rv[3]);
  Ro[1] = make_float4(rv[4], rv[5], rv[6], rv[7]);
}

// W3T[l][s][c][k] = w3[l][k][c*16+s]  (bf16) -> B-fragment is one contiguous short8
__global__ void k_w3cast(const float* __restrict__ w3, u16* __restrict__ w3t) {
  int idx = blockIdx.x * 256 + threadIdx.x;
  if (idx >= L_LAY * 64 * 1024) return;
  int l = idx >> 16;
  int r = idx & 65535;
  int k = r & 63;
  int c = (r >> 6) & 63;
  int s = r >> 12;
  w3t[idx] = f2bf(w3[(l * 64 + k) * 1024 + c * 16 + s]);
}

// ---- edge sort by receiver (receiver pattern identical for both layers) ----
__global__ void k_zero_deg(int* __restrict__ deg) {
  int i = blockIdx.x * 256 + threadIdx.x;
  if (i < N_NODES) deg[i] = 0;
}

__global__ void k_hist(const int* __restrict__ ei, int* __restrict__ deg) {
  int e = blockIdx.x * 256 + threadIdx.x;
  if (e >= N_EDGES) return;
  atomicAdd(&deg[ei[N_EDGES + e]], 1);
}

__global__ void __launch_bounds__(1024) k_scan(const int* __restrict__ deg,
                                               int* __restrict__ rowptr,
                                               int* __restrict__ woff) {
  __shared__ int wsum[16];
  __shared__ int carry_s;
  int tid = threadIdx.x;
  int lane = tid & 63, w = tid >> 6;
  if (tid == 0) carry_s = 0;
  __syncthreads();
  for (int base = 0; base < N_NODES; base += 1024) {
    int i = base + tid;
    int v = (i < N_NODES) ? deg[i] : 0;
    int orig = v;
#pragma unroll
    for (int off = 1; off < 64; off <<= 1) {
      int n = __shfl_up(v, off, 64);
      if (lane >= off) v += n;
    }
    if (lane == 63) wsum[w] = v;
    __syncthreads();
    if (w == 0 && lane < 16) {
      int x = wsum[lane];
#pragma unroll
      for (int off = 1; off < 16; off <<= 1) {
        int n = __shfl_up(x, off, 16);
        if (lane >= off) x += n;
      }
      wsum[lane] = x;
    }
    __syncthreads();
    int waveoff = (w > 0) ? wsum[w - 1] : 0;
    int carry = carry_s;
    int excl = carry + waveoff + v - orig;
    if (i < N_NODES) {
      rowptr[i] = excl;
      woff[i] = excl;
    }
    int tot = wsum[15];
    __syncthreads();
    if (tid == 0) carry_s = carry + tot;
    __syncthreads();
  }
  if (tid == 0) rowptr[N_NODES] = carry_s;
}

__global__ void k_permute(const int* __restrict__ ei, int* __restrict__ woff,
                          int* __restrict__ perm) {
  int e = blockIdx.x * 256 + threadIdx.x;
  if (e >= N_EDGES) return;
  int rdst = ei[N_EDGES + e];
  int pos = atomicAdd(&woff[rdst], 1);
  perm[pos] = e;
}

// edge MLP: per-wave slots, no inner syncthreads
__global__ void __launch_bounds__(256) k_edge_mlp(const float* __restrict__ rad,
                                                  const float* __restrict__ w1,
                                                  const float* __restrict__ w2,
                                                  u16* __restrict__ h2) {
  __shared__ float w1s[NB_R * HID_D];
  __shared__ float w2s[HID_D * HID_D];
  __shared__ float h1s[4][HID_D];
  int tid = threadIdx.x;
  for (int i = tid; i < NB_R * HID_D; i += 256) w1s[i] = w1[i];
  for (int i = tid; i < HID_D * HID_D; i += 256) w2s[i] = w2[i];
  __syncthreads();
  int slot = tid >> 6, t = tid & 63;
  for (int eb = blockIdx.x * 4; eb < N_EDGES; eb += gridDim.x * 4) {
    int e = eb + slot;
    float4 ra = *(const float4*)(rad + (size_t)e * 8);
    float4 rb = *(const float4*)(rad + (size_t)e * 8 + 4);
    float pre = ra.x * w1s[0 * 64 + t] + ra.y * w1s[1 * 64 + t] + ra.z * w1s[2 * 64 + t] +
                ra.w * w1s[3 * 64 + t] + rb.x * w1s[4 * 64 + t] + rb.y * w1s[5 * 64 + t] +
                rb.z * w1s[6 * 64 + t] + rb.w * w1s[7 * 64 + t];
    float h1 = pre / (1.0f + __expf(-pre));
    h1s[slot][t] = h1;
    float pre2 = 0.0f;
#pragma unroll
    for (int j = 0; j < HID_D; ++j) pre2 += h1s[slot][j] * w2s[j * HID_D + t];
    float h2v = pre2 / (1.0f + __expf(-pre2));
    h2[(size_t)e * HID_D + t] = f2bf(h2v);
  }
}

// up = feats @ W_up, scaled by 1/AVG_NEI (folded); per-wave slots, no inner syncs
__global__ void __launch_bounds__(256) k_up(const float* __restrict__ feats,
                                            const float* __restrict__ Wup,
                                            float* __restrict__ up) {
  __shared__ float ws[C_CH * C_CH];
  __shared__ float fs[4][C_CH];
  int tid = threadIdx.x;
  for (int i = tid; i < C_CH * C_CH; i += 256) ws[i] = Wup[i];
  __syncthreads();
  int slot = tid >> 6, t = tid & 63;
  for (int nb = blockIdx.x * 4; nb < N_NODES; nb += gridDim.x * 4) {
    int n = nb + slot;
    fs[slot][t] = feats[n * C_CH + t];
    float acc = 0.0f;
#pragma unroll
    for (int j = 0; j < C_CH; ++j) acc += fs[slot][j] * ws[j * C_CH + t];
    up[n * C_CH + t] = acc * INV_AVG;
  }
}

// Gather: wave owns 4 nodes; MFMA tile rows = 4 nodes x 4 sorted edges.
// acc[0..3] is a complete per-node edge reduction -> zero atomics, coalesced stores.
__global__ void __launch_bounds__(256) k_gather(const u16* __restrict__ h2,
                                                const u16* __restrict__ W3T,
                                                const float* __restrict__ up,
                                                const float* __restrict__ Y,
                                                const int* __restrict__ ei,
                                                const int* __restrict__ perm,
                                                const int* __restrict__ rowptr,
                                                float* __restrict__ Abuf) {
  __shared__ __align__(16) float Yt[4][16][16];
  int tid = threadIdx.x;
  int wv = tid >> 6, lane = tid & 63;
  int row = lane & 15, kg = lane >> 4;
  int col = row;
  int nb = (blockIdx.x * 4 + wv) * 4;
  int rp0 = rowptr[nb], rp1 = rowptr[nb + 1], rp2 = rowptr[nb + 2], rp3 = rowptr[nb + 3],
      rp4 = rowptr[nb + 4];
  int d0 = rp1 - rp0, d1 = rp2 - rp1, d2 = rp3 - rp2, d3 = rp4 - rp3;
  int rmax = max(max((d0 + 3) >> 2, (d1 + 3) >> 2), max((d2 + 3) >> 2, (d3 + 3) >> 2));
  rmax = max(rmax, 1);
  int nr = row >> 2;
  int baseA = nr == 0 ? rp0 : nr == 1 ? rp1 : nr == 2 ? rp2 : rp3;
  int degA = nr == 0 ? d0 : nr == 1 ? d1 : nr == 2 ? d2 : d3;
  int baseR = kg == 0 ? rp0 : kg == 1 ? rp1 : kg == 2 ? rp2 : rp3;
  int degR = kg == 0 ? d0 : kg == 1 ? d1 : kg == 2 ? d2 : d3;
  int nodeR = nb + kg;

  for (int r = 0; r < rmax; ++r) {
    // A fragment: row = node (row>>2), edge slot r*4 + (row&3)
    int sl = r * 4 + (row & 3);
    int eA = (sl < degA) ? perm[baseA + sl] : -1;
    short8 a0 = {0, 0, 0, 0, 0, 0, 0, 0};
    short8 a1 = {0, 0, 0, 0, 0, 0, 0, 0};
    float4 yq = make_float4(0.0f, 0.0f, 0.0f, 0.0f);
    if (eA >= 0) {
      a0 = *(const short8*)(h2 + (size_t)eA * 64 + kg * 8);
      a1 = *(const short8*)(h2 + (size_t)eA * 64 + 32 + kg * 8);
      yq = *(const float4*)(Y + (size_t)eA * 16 + kg * 4);
    }
    Yt[wv][kg * 4 + 0][row] = yq.x;
    Yt[wv][kg * 4 + 1][row] = yq.y;
    Yt[wv][kg * 4 + 2][row] = yq.z;
    Yt[wv][kg * 4 + 3][row] = yq.w;
    // reduction lanes: 4 edges of node kg; preload up[snd][c] for all 4 cgroups
    int snd[4];
#pragma unroll
    for (int q = 0; q < 4; ++q) {
      int slq = r * 4 + q;
      int eR = (slq < degR) ? perm[baseR + slq] : -1;
      snd[q] = (eR >= 0) ? ei[eR] : 0;
    }
    float upv[16];
#pragma unroll
    for (int cg = 0; cg < 4; ++cg)
#pragma unroll
      for (int q = 0; q < 4; ++q)
        upv[cg * 4 + q] = up[(size_t)snd[q] * 64 + cg * 16 + col];

#pragma unroll
    for (int cg = 0; cg < 4; ++cg) {
      float Areg[16];
#pragma unroll
      for (int s = 0; s < 16; ++s) {
        const u16* wp = W3T + ((s * 64 + cg * 16 + col) * 64) + kg * 8;
        short8 b0 = *(const short8*)(wp);
        short8 b1 = *(const short8*)(wp + 32);
        f32x4 acc = {0.0f, 0.0f, 0.0f, 0.0f};
        acc = __builtin_amdgcn_mfma_f32_16x16x32_bf16(a0, b0, acc, 0, 0, 0);
        acc = __builtin_amdgcn_mfma_f32_16x16x32_bf16(a1, b1, acc, 0, 0, 0);
        float4 yv = *(const float4*)&Yt[wv][s][kg * 4];
        Areg[s] = acc[0] * yv.x * upv[cg * 4 + 0] + acc[1] * yv.y * upv[cg * 4 + 1] +
                  acc[2] * yv.z * upv[cg * 4 + 2] + acc[3] * yv.w * upv[cg * 4 + 3];
      }
      float* dst = Abuf + (size_t)nodeR * 1024 + (cg * 16 + col) * 16;
      float4 o0 = make_float4(Areg[0], Areg[1], Areg[2], Areg[3]);
      float4 o1 = make_float4(Areg[4], Areg[5], Areg[6], Areg[7]);
      float4 o2 = make_float4(Areg[8], Areg[9], Areg[10], Areg[11]);
      float4 o3 = make_float4(Areg[12], Areg[13], Areg[14], Areg[15]);
      if (r > 0) {
        float4 p0 = *(const float4*)(dst + 0);
        float4 p1 = *(const float4*)(dst + 4);
        float4 p2 = *(const float4*)(dst + 8);
        float4 p3 = *(const float4*)(dst + 12);
        o0.x += p0.x; o0.y += p0.y; o0.z += p0.z; o0.w += p0.w;
        o1.x += p1.x; o1.y += p1.y; o1.z += p1.z; o1.w += p1.w;
        o2.x += p2.x; o2.y += p2.y; o2.z += p2.z; o2.w += p2.w;
        o3.x += p3.x; o3.y += p3.y; o3.z += p3.z; o3.w += p3.w;
      }
      *(float4*)(dst + 0) = o0;
      *(float4*)(dst + 4) = o1;
      *(float4*)(dst + 8) = o2;
      *(float4*)(dst + 12) = o3;
    }
  }
}

__global__ void __launch_bounds__(256) k_node_update(
    const float* __restrict__ Abuf, const float* __restrict__ featsOld,
    float* __restrict__ featsNew, const float* __restrict__ Wmix,
    const float* __restrict__ Wskip, const float* __restrict__ Wc,
    const float* __restrict__ Wout, const float* __restrict__ Wro,
    const int* __restrict__ species, const int* __restrict__ batch,
    const int* __restrict__ headArr, float* __restrict__ out) {
  __shared__ float Wmixs[C_CH * C_CH];
  __shared__ float Wouts[C_CH * C_CH];
  __shared__ __align__(16) float As[4 * C_CH * S_SPH];
  __shared__ float qs[4][C_CH];
  int tid = threadIdx.x;
  for (int i = tid; i < C_CH * C_CH; i += 256) {
    Wmixs[i] = Wmix[i];
    Wouts[i] = Wout[i];
  }
  size_t base = (size_t)blockIdx.x * 4 * C_CH * S_SPH;
  for (int i = tid; i < 4 * C_CH * S_SPH; i += 256) As[i] = Abuf[base + i];
  __syncthreads();
  int nl = tid >> 6, t = tid & 63;
  int node = blockIdx.x * 4 + nl;
  int sp = species[node];
  float A2[S_SPH];
#pragma unroll
  for (int s = 0; s < S_SPH; ++s) A2[s] = 0.0f;
  const float4* Ac = (const float4*)&As[nl * C_CH * S_SPH];
  for (int c = 0; c < C_CH; ++c) {
    float wm = Wmixs[c * C_CH + t];
    float4 v0 = Ac[c * 4 + 0], v1 = Ac[c * 4 + 1], v2 = Ac[c * 4 + 2], v3 = Ac[c * 4 + 3];
    A2[0] += wm * v0.x; A2[1] += wm * v0.y; A2[2] += wm * v0.z; A2[3] += wm * v0.w;
    A2[4] += wm * v1.x; A2[5] += wm * v1.y; A2[6] += wm * v1.z; A2[7] += wm * v1.w;
    A2[8] += wm * v2.x; A2[9] += wm * v2.y; A2[10] += wm * v2.z; A2[11] += wm * v2.w;
    A2[12] += wm * v3.x; A2[13] += wm * v3.y; A2[14] += wm * v3.z; A2[15] += wm * v3.w;
  }
  float p1 = A2[0];
  float p2 = 0.0f;
#pragma unroll
  for (int s = 0; s < S_SPH; ++s) p2 += A2[s] * A2[s];
  float p3 = p2 * p1;
  float q = Wc[(sp * 3 + 0) * C_CH + t] * p1 + Wc[(sp * 3 + 1) * C_CH + t] * p2 +
            Wc[(sp * 3 + 2) * C_CH + t] * p3;
  qs[nl][t] = q;
  float sc = 0.0f;
  for (int c = 0; c < C_CH; ++c)
    sc += featsOld[node * C_CH + c] * Wskip[(c * NE_EL + sp) * C_CH + t];
  __syncthreads();
  float nf = sc;
#pragma unroll
  for (int d = 0; d < C_CH; ++d) nf += qs[nl][d] * Wouts[d * C_CH + t];
  featsNew[node * C_CH + t] = nf;
  int b = batch[node];
  int h = headArr[b];
  float en = nf * Wro[t * N_HEADS + h];
#pragma unroll
  for (int off = 32; off; off >>= 1) en += __shfl_down(en, off, 64);
  if (t == 0) atomicAdd(&out[b], en);
}

extern "C" void kernel_launch(void* const* d_in, const int* in_sizes, int n_in,
                              void* d_out, int out_size, void* d_ws, size_t ws_size,
                              hipStream_t stream) {
  const float* pos = (const float*)d_in[0];
  const float* attrs = (const float*)d_in[1];
  const float* shifts = (const float*)d_in[2];
  const float* ae = (const float*)d_in[3];
  const float* Wemb = (const float*)d_in[4];
  const float* Wup = (const float*)d_in[5];
  const float* w1 = (const float*)d_in[6];
  const float* w2 = (const float*)d_in[7];
  const float* w3 = (const float*)d_in[8];
  const float* Wmix = (const float*)d_in[9];
  const float* Wskip = (const float*)d_in[10];
  const float* Wc = (const float*)d_in[11];
  const float* Wout = (const float*)d_in[12];
  const float* Wro = (const float*)d_in[13];
  const int* ei = (const int*)d_in[14];
  const int* batch = (const int*)d_in[15];
  const int* head = (const int*)d_in[16];
  float* out = (float*)d_out;

  char* p = (char*)d_ws;
  float* Y = (float*)p;      p += (size_t)N_EDGES * 16 * 4;
  float* rad = (float*)p;    p += (size_t)N_EDGES * 8 * 4;
  float* up = (float*)p;     p += (size_t)N_NODES * 64 * 4;
  float* fA = (float*)p;     p += (size_t)N_NODES * 64 * 4;
  float* fB = (float*)p;     p += (size_t)N_NODES * 64 * 4;
  float* Abuf = (float*)p;   p += (size_t)N_NODES * 1024 * 4;
  u16* h2 = (u16*)p;         p += (size_t)N_EDGES * 64 * 2;
  u16* W3T = (u16*)p;        p += (size_t)L_LAY * 65536 * 2;
  int* species = (int*)p;    p += (size_t)N_NODES * 4;
  int* deg = (int*)p;        p += (size_t)N_NODES * 4;
  int* rowptr = (int*)p;     p += (size_t)(N_NODES + 4) * 4;
  int* woff = (int*)p;       p += (size_t)N_NODES * 4;
  int* perm = (int*)p;       p += (size_t)N_EDGES * 4;
  if ((size_t)(p - (char*)d_ws) > ws_size) return;

  k_zero_out<<<1, 64, 0, stream>>>(out);
  k_node_init<<<(N_NODES + 255) / 256, 256, 0, stream>>>(attrs, ae, batch, head, species, out);
  k_embed<<<(N_NODES * C_CH + 255) / 256, 256, 0, stream>>>(species, Wemb, fA);
  k_geom<<<(N_EDGES + 255) / 256, 256, 0, stream>>>(pos, shifts, ei, Y, rad);
  k_w3cast<<<(L_LAY * 65536 + 255) / 256, 256, 0, stream>>>(w3, W3T);
  k_zero_deg<<<(N_NODES + 255) / 256, 256, 0, stream>>>(deg);
  k_hist<<<(N_EDGES + 255) / 256, 256, 0, stream>>>(ei, deg);
  k_scan<<<1, 1024, 0, stream>>>(deg, rowptr, woff);
  k_permute<<<(N_EDGES + 255) / 256, 256, 0, stream>>>(ei, woff, perm);

  const float* fOld = fA;
  float* fNew = fB;
  for (int l = 0; l < L_LAY; ++l) {
    k_edge_mlp<<<2048, 256, 0, stream>>>(rad, w1 + l * NB_R * HID_D, w2 + l * HID_D * HID_D, h2);
    k_up<<<512, 256, 0, stream>>>(fOld, Wup + l * C_CH * C_CH, up);
    k_gather<<<N_NODES / 16, 256, 0, stream>>>(h2, W3T + l * 65536, up, Y, ei, perm, rowptr, Abuf);
    k_node_update<<<N_NODES / 4, 256, 0, stream>>>(
        Abuf, fOld, fNew, Wmix + l * C_CH * C_CH, Wskip + l * C_CH * NE_EL * C_CH,
        Wc + l * NE_EL * 3 * C_CH, Wout + l * C_CH * C_CH, Wro + l * C_CH * N_HEADS,
        species, batch, head, out);
    const float* tmp = fNew;
    fNew = (float*)fOld;
    fOld = tmp;
  }
}

// Round 3
// 581.457 us; speedup vs baseline: 2.0064x; 2.0064x over previous
//
#include <hip/hip_runtime.h>

typedef unsigned short u16;
typedef unsigned int u32;
typedef __attribute__((ext_vector_type(8))) short short8;
typedef __attribute__((ext_vector_type(4))) float f32x4;

#define N_NODES 10000
#define N_EDGES 100000
#define C_CH 64
#define S_SPH 16
#define NB_R 8
#define HID_D 64
#define NE_EL 10
#define G_GR 64
#define L_LAY 2
#define N_HEADS 1
#define RCUT 5.0f
#define INV_AVG (1.0f/16.0f)

__device__ __forceinline__ u16 f2bf(float f) {
  u32 u = __float_as_uint(f);
  u32 r = (u + 0x7FFFu + ((u >> 16) & 1u)) >> 16;
  return (u16)r;
}

__global__ void k_zero_out(float* out) {
  if (threadIdx.x < G_GR) out[threadIdx.x] = 0.0f;
}

__global__ void k_node_init(const float* __restrict__ attrs, const float* __restrict__ ae,
                            const int* __restrict__ batch, const int* __restrict__ head,
                            int* __restrict__ species, float* __restrict__ out) {
  int n = blockIdx.x * 256 + threadIdx.x;
  if (n >= N_NODES) return;
  int sp = 0;
#pragma unroll
  for (int e = 0; e < NE_EL; ++e)
    if (attrs[n * NE_EL + e] > 0.5f) sp = e;
  species[n] = sp;
  int b = batch[n];
  int h = head[b];
  atomicAdd(&out[b], ae[h * NE_EL + sp]);
}

__global__ void k_embed(const int* __restrict__ species, const float* __restrict__ Wemb,
                        float* __restrict__ feats) {
  int idx = blockIdx.x * 256 + threadIdx.x;
  if (idx >= N_NODES * C_CH) return;
  feats[idx] = Wemb[species[idx >> 6] * C_CH + (idx & 63)];
}

// ---- edge sort by receiver (receiver pattern identical for both layers) ----
__global__ void k_zero_deg(int* __restrict__ deg) {
  int i = blockIdx.x * 256 + threadIdx.x;
  if (i < N_NODES) deg[i] = 0;
}

__global__ void k_hist(const int* __restrict__ ei, int* __restrict__ deg) {
  int e = blockIdx.x * 256 + threadIdx.x;
  if (e >= N_EDGES) return;
  atomicAdd(&deg[ei[N_EDGES + e]], 1);
}

__global__ void __launch_bounds__(1024) k_scan(const int* __restrict__ deg,
                                               int* __restrict__ rowptr,
                                               int* __restrict__ woff) {
  __shared__ int wsum[16];
  __shared__ int carry_s;
  int tid = threadIdx.x;
  int lane = tid & 63, w = tid >> 6;
  if (tid == 0) carry_s = 0;
  __syncthreads();
  for (int base = 0; base < N_NODES; base += 1024) {
    int i = base + tid;
    int v = (i < N_NODES) ? deg[i] : 0;
    int orig = v;
#pragma unroll
    for (int off = 1; off < 64; off <<= 1) {
      int n = __shfl_up(v, off, 64);
      if (lane >= off) v += n;
    }
    if (lane == 63) wsum[w] = v;
    __syncthreads();
    if (w == 0 && lane < 16) {
      int x = wsum[lane];
#pragma unroll
      for (int off = 1; off < 16; off <<= 1) {
        int n = __shfl_up(x, off, 16);
        if (lane >= off) x += n;
      }
      wsum[lane] = x;
    }
    __syncthreads();
    int waveoff = (w > 0) ? wsum[w - 1] : 0;
    int carry = carry_s;
    int excl = carry + waveoff + v - orig;
    if (i < N_NODES) {
      rowptr[i] = excl;
      woff[i] = excl;
    }
    int tot = wsum[15];
    __syncthreads();
    if (tid == 0) carry_s = carry + tot;
    __syncthreads();
  }
  if (tid == 0) rowptr[N_NODES] = carry_s;
}

// rank[e] = sorted position; sndp[pos] = sender of the edge at sorted position
__global__ void k_permute(const int* __restrict__ ei, int* __restrict__ woff,
                          int* __restrict__ rank, int* __restrict__ sndp) {
  int e = blockIdx.x * 256 + threadIdx.x;
  if (e >= N_EDGES) return;
  int rdst = ei[N_EDGES + e];
  int pos = atomicAdd(&woff[rdst], 1);
  rank[e] = pos;
  sndp[pos] = ei[e];
}

// geometry: writes Y and radial directly in receiver-sorted order (Yp/radp at rank[e])
__global__ void k_geom(const float* __restrict__ pos, const float* __restrict__ shifts,
                       const int* __restrict__ ei, const int* __restrict__ rank,
                       float* __restrict__ Yp, float* __restrict__ radp) {
  int e = blockIdx.x * 256 + threadIdx.x;
  if (e >= N_EDGES) return;
  int s = ei[e], r = ei[N_EDGES + e];
  float dx = pos[r * 3 + 0] - pos[s * 3 + 0] + shifts[e * 3 + 0];
  float dy = pos[r * 3 + 1] - pos[s * 3 + 1] + shifts[e * 3 + 1];
  float dz = pos[r * 3 + 2] - pos[s * 3 + 2] + shifts[e * 3 + 2];
  float rr = sqrtf(dx * dx + dy * dy + dz * dz);
  rr = fmaxf(rr, 1e-12f);
  float inv = 1.0f / rr;
  float x = dx * inv, y = dy * inv, z = dz * inv;
  float xx = x * x, yy = y * y, zz = z * z;
  const float s3 = 1.73205080757f, s5 = 2.2360679775f, s15 = 3.87298334621f;
  const float c1 = 2.09165006634f, c2 = 10.2469507659f, c3 = 1.62018517461f;
  const float c4 = 1.32287565553f, c5 = 5.12347538298f;
  int rk = rank[e];
  float4* Yo = (float4*)(Yp + (size_t)rk * 16);
  Yo[0] = make_float4(1.0f, s3 * x, s3 * y, s3 * z);
  Yo[1] = make_float4(s15 * x * y, s15 * y * z, 0.5f * s5 * (3.0f * zz - 1.0f), s15 * x * z);
  Yo[2] = make_float4(0.5f * s15 * (xx - yy), c1 * y * (3.0f * xx - yy), c2 * x * y * z,
                      c3 * y * (5.0f * zz - 1.0f));
  Yo[3] = make_float4(c4 * z * (5.0f * zz - 3.0f), c3 * x * (5.0f * zz - 1.0f),
                      c5 * z * (xx - yy), c1 * x * (xx - 3.0f * yy));
  float t = rr * (1.0f / RCUT);
  float t2 = t * t;
  float t6 = t2 * t2 * t2;
  float fcut = 1.0f - 28.0f * t6 + 48.0f * t6 * t - 21.0f * t6 * t2;
  if (rr >= RCUT) fcut = 0.0f;
  float pref = 0.63245553203f * inv * fcut;
  float arg = 3.14159265359f * rr * (1.0f / RCUT);
  float sa, ca;
  __sincosf(arg, &sa, &ca);
  float twoc = 2.0f * ca;
  float sprev = 0.0f, scur = sa;
  float rv[8];
#pragma unroll
  for (int n = 0; n < 8; ++n) {
    rv[n] = pref * scur;
    float snext = twoc * scur - sprev;
    sprev = scur;
    scur = snext;
  }
  float4* Ro = (float4*)(radp + (size_t)rk * 8);
  Ro[0] = make_float4(rv[0], rv[1], rv[2], rv[3]);
  Ro[1] = make_float4(rv[4], rv[5], rv[6], rv[7]);
}

// W3T[l][s][c][k] = w3[l][k][c*16+s]  (bf16) -> B-fragment is one contiguous short8
__global__ void k_w3cast(const float* __restrict__ w3, u16* __restrict__ w3t) {
  int idx = blockIdx.x * 256 + threadIdx.x;
  if (idx >= L_LAY * 64 * 1024) return;
  int l = idx >> 16;
  int r = idx & 65535;
  int k = r & 63;
  int c = (r >> 6) & 63;
  int s = r >> 12;
  w3t[idx] = f2bf(w3[(l * 64 + k) * 1024 + c * 16 + s]);
}

// edge MLP over receiver-sorted positions: fully coalesced read (radp) and write (h2)
__global__ void __launch_bounds__(256) k_edge_mlp(const float* __restrict__ radp,
                                                  const float* __restrict__ w1,
                                                  const float* __restrict__ w2,
                                                  u16* __restrict__ h2) {
  __shared__ float w1s[NB_R * HID_D];
  __shared__ float w2s[HID_D * HID_D];
  __shared__ float h1s[4][HID_D];
  int tid = threadIdx.x;
  for (int i = tid; i < NB_R * HID_D; i += 256) w1s[i] = w1[i];
  for (int i = tid; i < HID_D * HID_D; i += 256) w2s[i] = w2[i];
  __syncthreads();
  int slot = tid >> 6, t = tid & 63;
  for (int eb = blockIdx.x * 4; eb < N_EDGES; eb += gridDim.x * 4) {
    int e = eb + slot;
    float4 ra = *(const float4*)(radp + (size_t)e * 8);
    float4 rb = *(const float4*)(radp + (size_t)e * 8 + 4);
    float pre = ra.x * w1s[0 * 64 + t] + ra.y * w1s[1 * 64 + t] + ra.z * w1s[2 * 64 + t] +
                ra.w * w1s[3 * 64 + t] + rb.x * w1s[4 * 64 + t] + rb.y * w1s[5 * 64 + t] +
                rb.z * w1s[6 * 64 + t] + rb.w * w1s[7 * 64 + t];
    float h1 = pre / (1.0f + __expf(-pre));
    h1s[slot][t] = h1;
    float pre2 = 0.0f;
#pragma unroll
    for (int j = 0; j < HID_D; ++j) pre2 += h1s[slot][j] * w2s[j * HID_D + t];
    float h2v = pre2 / (1.0f + __expf(-pre2));
    h2[(size_t)e * HID_D + t] = f2bf(h2v);
  }
}

// up = feats @ W_up, scaled by 1/AVG_NEI (folded)
__global__ void __launch_bounds__(256) k_up(const float* __restrict__ feats,
                                            const float* __restrict__ Wup,
                                            float* __restrict__ up) {
  __shared__ float ws[C_CH * C_CH];
  __shared__ float fs[4][C_CH];
  int tid = threadIdx.x;
  for (int i = tid; i < C_CH * C_CH; i += 256) ws[i] = Wup[i];
  __syncthreads();
  int slot = tid >> 6, t = tid & 63;
  for (int nb = blockIdx.x * 4; nb < N_NODES; nb += gridDim.x * 4) {
    int n = nb + slot;
    fs[slot][t] = feats[n * C_CH + t];
    float acc = 0.0f;
#pragma unroll
    for (int j = 0; j < C_CH; ++j) acc += fs[slot][j] * ws[j * C_CH + t];
    up[n * C_CH + t] = acc * INV_AVG;
  }
}

// Gather: wave owns 4 nodes; MFMA tile rows = 4 nodes x 4 sorted edges.
// cg-outer loop: register accumulator Areg[16] held across all edge iterations,
// W3T cg-chunk staged in LDS (pitch 72 u16 -> conflict-free b128), Abuf written ONCE.
__global__ void __launch_bounds__(256) k_gather(const u16* __restrict__ h2,
                                                const u16* __restrict__ W3T,
                                                const float* __restrict__ up,
                                                const float* __restrict__ Yp,
                                                const int* __restrict__ sndp,
                                                const int* __restrict__ rowptr,
                                                float* __restrict__ Abuf) {
  __shared__ __align__(16) u16 w3s[16 * 16 * 72];  // [s][c'][k pad 72] = 36 KB
  __shared__ __align__(16) float Yt[4][16][16];    // 4 KB
  int tid = threadIdx.x;
  int wv = tid >> 6, lane = tid & 63;
  int row = lane & 15, kg = lane >> 4;
  int col = row;
  int nb = (blockIdx.x * 4 + wv) * 4;
  int rp0 = rowptr[nb], rp1 = rowptr[nb + 1], rp2 = rowptr[nb + 2], rp3 = rowptr[nb + 3],
      rp4 = rowptr[nb + 4];
  int d0 = rp1 - rp0, d1 = rp2 - rp1, d2 = rp3 - rp2, d3 = rp4 - rp3;
  int rmax = max(max((d0 + 3) >> 2, (d1 + 3) >> 2), max((d2 + 3) >> 2, (d3 + 3) >> 2));
  rmax = max(rmax, 1);
  int nr = row >> 2;
  int baseA = nr == 0 ? rp0 : nr == 1 ? rp1 : nr == 2 ? rp2 : rp3;
  int degA = nr == 0 ? d0 : nr == 1 ? d1 : nr == 2 ? d2 : d3;
  int baseR = kg == 0 ? rp0 : kg == 1 ? rp1 : kg == 2 ? rp2 : rp3;
  int degR = kg == 0 ? d0 : kg == 1 ? d1 : kg == 2 ? d2 : d3;
  int nodeR = nb + kg;

#pragma unroll 1
  for (int cg = 0; cg < 4; ++cg) {
    __syncthreads();
    for (int idx = tid; idx < 2048; idx += 256) {
      int s = idx >> 7, c = (idx >> 3) & 15, ck = (idx & 7) * 8;
      *(short8*)&w3s[(s * 16 + c) * 72 + ck] =
          *(const short8*)(W3T + (((s * 64 + cg * 16 + c) << 6) + ck));
    }
    __syncthreads();
    float Areg[16];
#pragma unroll
    for (int s = 0; s < 16; ++s) Areg[s] = 0.0f;
#pragma unroll 1
    for (int r = 0; r < rmax; ++r) {
      int sl = r * 4 + (row & 3);
      short8 a0 = {0, 0, 0, 0, 0, 0, 0, 0};
      short8 a1 = {0, 0, 0, 0, 0, 0, 0, 0};
      float4 yq = make_float4(0.0f, 0.0f, 0.0f, 0.0f);
      if (sl < degA) {
        int eA = baseA + sl;
        a0 = *(const short8*)(h2 + (size_t)eA * 64 + kg * 8);
        a1 = *(const short8*)(h2 + (size_t)eA * 64 + 32 + kg * 8);
        yq = *(const float4*)(Yp + (size_t)eA * 16 + kg * 4);
      }
      Yt[wv][kg * 4 + 0][row] = yq.x;
      Yt[wv][kg * 4 + 1][row] = yq.y;
      Yt[wv][kg * 4 + 2][row] = yq.z;
      Yt[wv][kg * 4 + 3][row] = yq.w;
      float upv[4];
#pragma unroll
      for (int q = 0; q < 4; ++q) {
        int slq = r * 4 + q;
        int sq = (slq < degR) ? sndp[baseR + slq] : 0;
        upv[q] = up[(size_t)sq * 64 + cg * 16 + col];
      }
#pragma unroll
      for (int s = 0; s < 16; ++s) {
        const u16* wp = w3s + (s * 16 + col) * 72 + kg * 8;
        short8 b0 = *(const short8*)wp;
        short8 b1 = *(const short8*)(wp + 32);
        f32x4 acc = {0.0f, 0.0f, 0.0f, 0.0f};
        acc = __builtin_amdgcn_mfma_f32_16x16x32_bf16(a0, b0, acc, 0, 0, 0);
        acc = __builtin_amdgcn_mfma_f32_16x16x32_bf16(a1, b1, acc, 0, 0, 0);
        float4 yv = *(const float4*)&Yt[wv][s][kg * 4];
        Areg[s] += acc[0] * yv.x * upv[0] + acc[1] * yv.y * upv[1] + acc[2] * yv.z * upv[2] +
                   acc[3] * yv.w * upv[3];
      }
    }
    float* dst = Abuf + (size_t)nodeR * 1024 + (cg * 16 + col) * 16;
    *(float4*)(dst + 0) = make_float4(Areg[0], Areg[1], Areg[2], Areg[3]);
    *(float4*)(dst + 4) = make_float4(Areg[4], Areg[5], Areg[6], Areg[7]);
    *(float4*)(dst + 8) = make_float4(Areg[8], Areg[9], Areg[10], Areg[11]);
    *(float4*)(dst + 12) = make_float4(Areg[12], Areg[13], Areg[14], Areg[15]);
  }
}

__global__ void __launch_bounds__(256) k_node_update(
    const float* __restrict__ Abuf, const float* __restrict__ featsOld,
    float* __restrict__ featsNew, const float* __restrict__ Wmix,
    const float* __restrict__ Wskip, const float* __restrict__ Wc,
    const float* __restrict__ Wout, const float* __restrict__ Wro,
    const int* __restrict__ species, const int* __restrict__ batch,
    const int* __restrict__ headArr, float* __restrict__ out) {
  __shared__ float Wmixs[C_CH * C_CH];
  __shared__ float Wouts[C_CH * C_CH];
  __shared__ __align__(16) float As[4 * C_CH * S_SPH];
  __shared__ float qs[4][C_CH];
  int tid = threadIdx.x;
  for (int i = tid; i < C_CH * C_CH; i += 256) {
    Wmixs[i] = Wmix[i];
    Wouts[i] = Wout[i];
  }
  size_t base = (size_t)blockIdx.x * 4 * C_CH * S_SPH;
  for (int i = tid; i < 4 * C_CH * S_SPH; i += 256) As[i] = Abuf[base + i];
  __syncthreads();
  int nl = tid >> 6, t = tid & 63;
  int node = blockIdx.x * 4 + nl;
  int sp = species[node];
  float A2[S_SPH];
#pragma unroll
  for (int s = 0; s < S_SPH; ++s) A2[s] = 0.0f;
  const float4* Ac = (const float4*)&As[nl * C_CH * S_SPH];
  for (int c = 0; c < C_CH; ++c) {
    float wm = Wmixs[c * C_CH + t];
    float4 v0 = Ac[c * 4 + 0], v1 = Ac[c * 4 + 1], v2 = Ac[c * 4 + 2], v3 = Ac[c * 4 + 3];
    A2[0] += wm * v0.x; A2[1] += wm * v0.y; A2[2] += wm * v0.z; A2[3] += wm * v0.w;
    A2[4] += wm * v1.x; A2[5] += wm * v1.y; A2[6] += wm * v1.z; A2[7] += wm * v1.w;
    A2[8] += wm * v2.x; A2[9] += wm * v2.y; A2[10] += wm * v2.z; A2[11] += wm * v2.w;
    A2[12] += wm * v3.x; A2[13] += wm * v3.y; A2[14] += wm * v3.z; A2[15] += wm * v3.w;
  }
  float p1 = A2[0];
  float p2 = 0.0f;
#pragma unroll
  for (int s = 0; s < S_SPH; ++s) p2 += A2[s] * A2[s];
  float p3 = p2 * p1;
  float q = Wc[(sp * 3 + 0) * C_CH + t] * p1 + Wc[(sp * 3 + 1) * C_CH + t] * p2 +
            Wc[(sp * 3 + 2) * C_CH + t] * p3;
  qs[nl][t] = q;
  float sc = 0.0f;
  for (int c = 0; c < C_CH; ++c)
    sc += featsOld[node * C_CH + c] * Wskip[(c * NE_EL + sp) * C_CH + t];
  __syncthreads();
  float nf = sc;
#pragma unroll
  for (int d = 0; d < C_CH; ++d) nf += qs[nl][d] * Wouts[d * C_CH + t];
  featsNew[node * C_CH + t] = nf;
  int b = batch[node];
  int h = headArr[b];
  float en = nf * Wro[t * N_HEADS + h];
#pragma unroll
  for (int off = 32; off; off >>= 1) en += __shfl_down(en, off, 64);
  if (t == 0) atomicAdd(&out[b], en);
}

extern "C" void kernel_launch(void* const* d_in, const int* in_sizes, int n_in,
                              void* d_out, int out_size, void* d_ws, size_t ws_size,
                              hipStream_t stream) {
  const float* pos = (const float*)d_in[0];
  const float* attrs = (const float*)d_in[1];
  const float* shifts = (const float*)d_in[2];
  const float* ae = (const float*)d_in[3];
  const float* Wemb = (const float*)d_in[4];
  const float* Wup = (const float*)d_in[5];
  const float* w1 = (const float*)d_in[6];
  const float* w2 = (const float*)d_in[7];
  const float* w3 = (const float*)d_in[8];
  const float* Wmix = (const float*)d_in[9];
  const float* Wskip = (const float*)d_in[10];
  const float* Wc = (const float*)d_in[11];
  const float* Wout = (const float*)d_in[12];
  const float* Wro = (const float*)d_in[13];
  const int* ei = (const int*)d_in[14];
  const int* batch = (const int*)d_in[15];
  const int* head = (const int*)d_in[16];
  float* out = (float*)d_out;

  char* p = (char*)d_ws;
  float* Yp = (float*)p;     p += (size_t)N_EDGES * 16 * 4;
  float* radp = (float*)p;   p += (size_t)N_EDGES * 8 * 4;
  float* up = (float*)p;     p += (size_t)N_NODES * 64 * 4;
  float* fA = (float*)p;     p += (size_t)N_NODES * 64 * 4;
  float* fB = (float*)p;     p += (size_t)N_NODES * 64 * 4;
  float* Abuf = (float*)p;   p += (size_t)N_NODES * 1024 * 4;
  u16* h2 = (u16*)p;         p += (size_t)N_EDGES * 64 * 2;
  u16* W3T = (u16*)p;        p += (size_t)L_LAY * 65536 * 2;
  int* species = (int*)p;    p += (size_t)N_NODES * 4;
  int* deg = (int*)p;        p += (size_t)N_NODES * 4;
  int* rowptr = (int*)p;     p += (size_t)(N_NODES + 4) * 4;
  int* woff = (int*)p;       p += (size_t)N_NODES * 4;
  int* rank = (int*)p;       p += (size_t)N_EDGES * 4;
  int* sndp = (int*)p;       p += (size_t)N_EDGES * 4;
  if ((size_t)(p - (char*)d_ws) > ws_size) return;

  k_zero_out<<<1, 64, 0, stream>>>(out);
  k_node_init<<<(N_NODES + 255) / 256, 256, 0, stream>>>(attrs, ae, batch, head, species, out);
  k_embed<<<(N_NODES * C_CH + 255) / 256, 256, 0, stream>>>(species, Wemb, fA);
  k_zero_deg<<<(N_NODES + 255) / 256, 256, 0, stream>>>(deg);
  k_hist<<<(N_EDGES + 255) / 256, 256, 0, stream>>>(ei, deg);
  k_scan<<<1, 1024, 0, stream>>>(deg, rowptr, woff);
  k_permute<<<(N_EDGES + 255) / 256, 256, 0, stream>>>(ei, woff, rank, sndp);
  k_geom<<<(N_EDGES + 255) / 256, 256, 0, stream>>>(pos, shifts, ei, rank, Yp, radp);
  k_w3cast<<<(L_LAY * 65536 + 255) / 256, 256, 0, stream>>>(w3, W3T);

  const float* fOld = fA;
  float* fNew = fB;
  for (int l = 0; l < L_LAY; ++l) {
    k_edge_mlp<<<2048, 256, 0, stream>>>(radp, w1 + l * NB_R * HID_D, w2 + l * HID_D * HID_D, h2);
    k_up<<<512, 256, 0, stream>>>(fOld, Wup + l * C_CH * C_CH, up);
    k_gather<<<N_NODES / 16, 256, 0, stream>>>(h2, W3T + l * 65536, up, Yp, sndp, rowptr, Abuf);
    k_node_update<<<N_NODES / 4, 256, 0, stream>>>(
        Abuf, fOld, fNew, Wmix + l * C_CH * C_CH, Wskip + l * C_CH * NE_EL * C_CH,
        Wc + l * NE_EL * 3 * C_CH, Wout + l * C_CH * C_CH, Wro + l * C_CH * N_HEADS,
        species, batch, head, out);
    const float* tmp = fNew;
    fNew = (float*)fOld;
    fOld = tmp;
  }
}

// Round 4
// 529.585 us; speedup vs baseline: 2.2029x; 1.0979x over previous
//
#include <hip/hip_runtime.h>

typedef unsigned short u16;
typedef unsigned int u32;
typedef __attribute__((ext_vector_type(8))) short short8;
typedef __attribute__((ext_vector_type(4))) float f32x4;

#define N_NODES 10000
#define N_EDGES 100000
#define C_CH 64
#define S_SPH 16
#define NB_R 8
#define HID_D 64
#define NE_EL 10
#define G_GR 64
#define L_LAY 2
#define N_HEADS 1
#define RCUT 5.0f
#define INV_AVG (1.0f/16.0f)

__device__ __forceinline__ u16 f2bf(float f) {
  u32 u = __float_as_uint(f);
  u32 r = (u + 0x7FFFu + ((u >> 16) & 1u)) >> 16;
  return (u16)r;
}

__global__ void k_init0(float* __restrict__ out, int* __restrict__ deg) {
  int i = blockIdx.x * 256 + threadIdx.x;
  if (i < G_GR) out[i] = 0.0f;
  if (i < N_NODES) deg[i] = 0;
}

__global__ void k_node_init(const float* __restrict__ attrs, const float* __restrict__ ae,
                            const int* __restrict__ batch, const int* __restrict__ head,
                            int* __restrict__ species, float* __restrict__ out) {
  int n = blockIdx.x * 256 + threadIdx.x;
  if (n >= N_NODES) return;
  int sp = 0;
#pragma unroll
  for (int e = 0; e < NE_EL; ++e)
    if (attrs[n * NE_EL + e] > 0.5f) sp = e;
  species[n] = sp;
  int b = batch[n];
  int h = head[b];
  atomicAdd(&out[b], ae[h * NE_EL + sp]);
}

__global__ void k_embed(const int* __restrict__ species, const float* __restrict__ Wemb,
                        float* __restrict__ feats) {
  int idx = blockIdx.x * 256 + threadIdx.x;
  if (idx >= N_NODES * C_CH) return;
  feats[idx] = Wemb[species[idx >> 6] * C_CH + (idx & 63)];
}

__global__ void k_hist(const int* __restrict__ ei, int* __restrict__ deg) {
  int e = blockIdx.x * 256 + threadIdx.x;
  if (e >= N_EDGES) return;
  atomicAdd(&deg[ei[N_EDGES + e]], 1);
}

__global__ void __launch_bounds__(1024) k_scan(const int* __restrict__ deg,
                                               int* __restrict__ rowptr,
                                               int* __restrict__ woff) {
  __shared__ int wsum[16];
  __shared__ int carry_s;
  int tid = threadIdx.x;
  int lane = tid & 63, w = tid >> 6;
  if (tid == 0) carry_s = 0;
  __syncthreads();
  for (int base = 0; base < N_NODES; base += 1024) {
    int i = base + tid;
    int v = (i < N_NODES) ? deg[i] : 0;
    int orig = v;
#pragma unroll
    for (int off = 1; off < 64; off <<= 1) {
      int n = __shfl_up(v, off, 64);
      if (lane >= off) v += n;
    }
    if (lane == 63) wsum[w] = v;
    __syncthreads();
    if (w == 0 && lane < 16) {
      int x = wsum[lane];
#pragma unroll
      for (int off = 1; off < 16; off <<= 1) {
        int n = __shfl_up(x, off, 16);
        if (lane >= off) x += n;
      }
      wsum[lane] = x;
    }
    __syncthreads();
    int waveoff = (w > 0) ? wsum[w - 1] : 0;
    int carry = carry_s;
    int excl = carry + waveoff + v - orig;
    if (i < N_NODES) {
      rowptr[i] = excl;
      woff[i] = excl;
    }
    int tot = wsum[15];
    __syncthreads();
    if (tid == 0) carry_s = carry + tot;
    __syncthreads();
  }
  if (tid == 0) rowptr[N_NODES] = carry_s;
}

__global__ void k_permute(const int* __restrict__ ei, int* __restrict__ woff,
                          int* __restrict__ rank, int* __restrict__ sndp) {
  int e = blockIdx.x * 256 + threadIdx.x;
  if (e >= N_EDGES) return;
  int rdst = ei[N_EDGES + e];
  int pos = atomicAdd(&woff[rdst], 1);
  rank[e] = pos;
  sndp[pos] = ei[e];
}

__global__ void k_geom(const float* __restrict__ pos, const float* __restrict__ shifts,
                       const int* __restrict__ ei, const int* __restrict__ rank,
                       float* __restrict__ Yp, float* __restrict__ radp) {
  int e = blockIdx.x * 256 + threadIdx.x;
  if (e >= N_EDGES) return;
  int s = ei[e], r = ei[N_EDGES + e];
  float dx = pos[r * 3 + 0] - pos[s * 3 + 0] + shifts[e * 3 + 0];
  float dy = pos[r * 3 + 1] - pos[s * 3 + 1] + shifts[e * 3 + 1];
  float dz = pos[r * 3 + 2] - pos[s * 3 + 2] + shifts[e * 3 + 2];
  float rr = sqrtf(dx * dx + dy * dy + dz * dz);
  rr = fmaxf(rr, 1e-12f);
  float inv = 1.0f / rr;
  float x = dx * inv, y = dy * inv, z = dz * inv;
  float xx = x * x, yy = y * y, zz = z * z;
  const float s3 = 1.73205080757f, s5 = 2.2360679775f, s15 = 3.87298334621f;
  const float c1 = 2.09165006634f, c2 = 10.2469507659f, c3 = 1.62018517461f;
  const float c4 = 1.32287565553f, c5 = 5.12347538298f;
  int rk = rank[e];
  float4* Yo = (float4*)(Yp + (size_t)rk * 16);
  Yo[0] = make_float4(1.0f, s3 * x, s3 * y, s3 * z);
  Yo[1] = make_float4(s15 * x * y, s15 * y * z, 0.5f * s5 * (3.0f * zz - 1.0f), s15 * x * z);
  Yo[2] = make_float4(0.5f * s15 * (xx - yy), c1 * y * (3.0f * xx - yy), c2 * x * y * z,
                      c3 * y * (5.0f * zz - 1.0f));
  Yo[3] = make_float4(c4 * z * (5.0f * zz - 3.0f), c3 * x * (5.0f * zz - 1.0f),
                      c5 * z * (xx - yy), c1 * x * (xx - 3.0f * yy));
  float t = rr * (1.0f / RCUT);
  float t2 = t * t;
  float t6 = t2 * t2 * t2;
  float fcut = 1.0f - 28.0f * t6 + 48.0f * t6 * t - 21.0f * t6 * t2;
  if (rr >= RCUT) fcut = 0.0f;
  float pref = 0.63245553203f * inv * fcut;
  float arg = 3.14159265359f * rr * (1.0f / RCUT);
  float sa, ca;
  __sincosf(arg, &sa, &ca);
  float twoc = 2.0f * ca;
  float sprev = 0.0f, scur = sa;
  float rv[8];
#pragma unroll
  for (int n = 0; n < 8; ++n) {
    rv[n] = pref * scur;
    float snext = twoc * scur - sprev;
    sprev = scur;
    scur = snext;
  }
  float4* Ro = (float4*)(radp + (size_t)rk * 8);
  Ro[0] = make_float4(rv[0], rv[1], rv[2], rv[3]);
  Ro[1] = make_float4(rv[4], rv[5], rv[6], rv[7]);
}

// W3T[l][s][c][k] bf16; w2T[l][t][j] bf16
__global__ void k_prep(const float* __restrict__ w3, const float* __restrict__ w2,
                       u16* __restrict__ w3t, u16* __restrict__ w2t) {
  int idx = blockIdx.x * 256 + threadIdx.x;
  if (idx < L_LAY * 65536) {
    int l = idx >> 16;
    int r = idx & 65535;
    int k = r & 63;
    int c = (r >> 6) & 63;
    int s = r >> 12;
    w3t[idx] = f2bf(w3[(l * 64 + k) * 1024 + c * 16 + s]);
  } else if (idx < L_LAY * 65536 + L_LAY * 4096) {
    int i = idx - L_LAY * 65536;
    int l = i >> 12;
    int r = i & 4095;
    int t = r >> 6;
    int j = r & 63;
    w2t[l * 4096 + t * 64 + j] = f2bf(w2[(l * 64 + j) * 64 + t]);
  }
}

// edge MLP, MFMA layer-2: 1 wave = 16 edges. h1 staged bf16 in LDS, XOR-swizzled.
__global__ void __launch_bounds__(64) k_edge_mlp(const float* __restrict__ radp,
                                                 const float* __restrict__ w1,
                                                 const u16* __restrict__ w2T,
                                                 u16* __restrict__ h2) {
  __shared__ float w1s[NB_R * HID_D];
  __shared__ __align__(16) u16 h1b[16 * 64];
  int lane = threadIdx.x;
  for (int i = lane; i < NB_R * HID_D; i += 64) w1s[i] = w1[i];
  int er = lane & 15, jg = lane >> 4;
  int eb = blockIdx.x * 16;
  int e = eb + er;
  float4 ra = *(const float4*)(radp + (size_t)e * 8);
  float4 rb = *(const float4*)(radp + (size_t)e * 8 + 4);
  float rv[8] = {ra.x, ra.y, ra.z, ra.w, rb.x, rb.y, rb.z, rb.w};
  u32* hb = (u32*)h1b;
#pragma unroll
  for (int jj = 0; jj < 16; jj += 2) {
    float p0 = 0.f, p1 = 0.f;
#pragma unroll
    for (int k = 0; k < 8; ++k) {
      p0 += rv[k] * w1s[k * 64 + jg * 16 + jj];
      p1 += rv[k] * w1s[k * 64 + jg * 16 + jj + 1];
    }
    p0 = p0 / (1.f + __expf(-p0));
    p1 = p1 / (1.f + __expf(-p1));
    u32 packed = (u32)f2bf(p0) | ((u32)f2bf(p1) << 16);
    int d = jg * 8 + (jj >> 1);
    hb[er * 32 + (d ^ ((er & 7) << 2))] = packed;
  }
  // layer 2: rows = 16 edges, cols = 64 hidden, K = 64
  int row = er, kg = jg, col = er;
  const u32* hbr = (const u32*)h1b;
  short8 a0 = *(const short8*)&hbr[row * 32 + ((kg * 4) ^ ((row & 7) << 2))];
  short8 a1 = *(const short8*)&hbr[row * 32 + ((16 + kg * 4) ^ ((row & 7) << 2))];
#pragma unroll
  for (int ch = 0; ch < 4; ++ch) {
    const u16* wp = w2T + (ch * 16 + col) * 64 + kg * 8;
    short8 b0 = *(const short8*)wp;
    short8 b1 = *(const short8*)(wp + 32);
    f32x4 acc = {0.f, 0.f, 0.f, 0.f};
    acc = __builtin_amdgcn_mfma_f32_16x16x32_bf16(a0, b0, acc, 0, 0, 0);
    acc = __builtin_amdgcn_mfma_f32_16x16x32_bf16(a1, b1, acc, 0, 0, 0);
#pragma unroll
    for (int rr = 0; rr < 4; ++rr) {
      float v = acc[rr];
      v = v / (1.f + __expf(-v));
      h2[(size_t)(eb + kg * 4 + rr) * 64 + ch * 16 + col] = f2bf(v);
    }
  }
}

// up = feats @ W_up * INV_AVG (node buffer)
__global__ void __launch_bounds__(256) k_up(const float* __restrict__ feats,
                                            const float* __restrict__ Wup,
                                            float* __restrict__ up) {
  __shared__ float ws[C_CH * C_CH];
  __shared__ float fs[4][C_CH];
  int tid = threadIdx.x;
  for (int i = tid; i < C_CH * C_CH; i += 256) ws[i] = Wup[i];
  __syncthreads();
  int slot = tid >> 6, t = tid & 63;
  for (int nb = blockIdx.x * 4; nb < N_NODES; nb += gridDim.x * 4) {
    int n = nb + slot;
    fs[slot][t] = feats[n * C_CH + t];
    float acc = 0.0f;
#pragma unroll
    for (int j = 0; j < C_CH; ++j) acc += fs[slot][j] * ws[j * C_CH + t];
    up[n * C_CH + t] = acc * INV_AVG;
  }
}

// upe[pos][c] = up[sndp[pos]][c]  -- converts gather's random up-read into a stream
__global__ void __launch_bounds__(256) k_upe(const float* __restrict__ up,
                                             const int* __restrict__ sndp,
                                             float* __restrict__ upe) {
  int tid = threadIdx.x;
  int slot = tid >> 6, t = tid & 63;
  for (int pb = blockIdx.x * 4; pb < N_EDGES; pb += gridDim.x * 4) {
    int pos = pb + slot;
    upe[(size_t)pos * 64 + t] = up[(size_t)sndp[pos] * 64 + t];
  }
}

// Gather v3: 1 wave per block, 4 nodes per wave. B-fragments in registers
// (8 s-half chunk), no W3 LDS; upe streamed; Abuf written once.
__global__ void __launch_bounds__(64) k_gather(const u16* __restrict__ h2,
                                               const u16* __restrict__ W3T,
                                               const float* __restrict__ upe,
                                               const float* __restrict__ Yp,
                                               const int* __restrict__ rowptr,
                                               float* __restrict__ Abuf) {
  __shared__ __align__(16) float Yt[16][20];
  int lane = threadIdx.x;
  int row = lane & 15, kg = lane >> 4;
  int col = row;
  int nb = blockIdx.x * 4;
  int rp0 = rowptr[nb], rp1 = rowptr[nb + 1], rp2 = rowptr[nb + 2], rp3 = rowptr[nb + 3],
      rp4 = rowptr[nb + 4];
  int d0 = rp1 - rp0, d1 = rp2 - rp1, d2 = rp3 - rp2, d3 = rp4 - rp3;
  int rmax = max(max((d0 + 3) >> 2, (d1 + 3) >> 2), max((d2 + 3) >> 2, (d3 + 3) >> 2));
  rmax = max(rmax, 1);
  int nr = row >> 2;
  int baseA = nr == 0 ? rp0 : nr == 1 ? rp1 : nr == 2 ? rp2 : rp3;
  int degA = nr == 0 ? d0 : nr == 1 ? d1 : nr == 2 ? d2 : d3;
  int baseR = kg == 0 ? rp0 : kg == 1 ? rp1 : kg == 2 ? rp2 : rp3;
  int degR = kg == 0 ? d0 : kg == 1 ? d1 : kg == 2 ? d2 : d3;
  int nodeR = nb + kg;

#pragma unroll 1
  for (int cg = 0; cg < 4; ++cg) {
#pragma unroll 1
    for (int hf = 0; hf < 2; ++hf) {
      short8 B0[8], B1[8];
#pragma unroll
      for (int ss = 0; ss < 8; ++ss) {
        int s = hf * 8 + ss;
        const u16* wp = W3T + (((s * 64 + cg * 16 + col) << 6) + kg * 8);
        B0[ss] = *(const short8*)wp;
        B1[ss] = *(const short8*)(wp + 32);
      }
      float Areg[8];
#pragma unroll
      for (int ss = 0; ss < 8; ++ss) Areg[ss] = 0.f;
#pragma unroll 1
      for (int r = 0; r < rmax; ++r) {
        int sl = r * 4 + (row & 3);
        short8 a0 = {0, 0, 0, 0, 0, 0, 0, 0};
        short8 a1 = {0, 0, 0, 0, 0, 0, 0, 0};
        float4 yq = make_float4(0.f, 0.f, 0.f, 0.f);
        if (sl < degA) {
          int eA = baseA + sl;
          a0 = *(const short8*)(h2 + (size_t)eA * 64 + kg * 8);
          a1 = *(const short8*)(h2 + (size_t)eA * 64 + 32 + kg * 8);
          yq = *(const float4*)(Yp + (size_t)eA * 16 + kg * 4);
        }
        Yt[kg * 4 + 0][row] = yq.x;
        Yt[kg * 4 + 1][row] = yq.y;
        Yt[kg * 4 + 2][row] = yq.z;
        Yt[kg * 4 + 3][row] = yq.w;
        float upv[4];
#pragma unroll
        for (int q = 0; q < 4; ++q) {
          int slq = r * 4 + q;
          int pos = (slq < degR) ? (baseR + slq) : 0;
          float u = upe[(size_t)pos * 64 + cg * 16 + col];
          upv[q] = (slq < degR) ? u : 0.f;
        }
#pragma unroll
        for (int ss = 0; ss < 8; ++ss) {
          f32x4 acc = {0.f, 0.f, 0.f, 0.f};
          acc = __builtin_amdgcn_mfma_f32_16x16x32_bf16(a0, B0[ss], acc, 0, 0, 0);
          acc = __builtin_amdgcn_mfma_f32_16x16x32_bf16(a1, B1[ss], acc, 0, 0, 0);
          float4 yv = *(const float4*)&Yt[hf * 8 + ss][kg * 4];
          Areg[ss] += acc[0] * yv.x * upv[0] + acc[1] * yv.y * upv[1] + acc[2] * yv.z * upv[2] +
                      acc[3] * yv.w * upv[3];
        }
      }
      float* dst = Abuf + (size_t)nodeR * 1024 + (cg * 16 + col) * 16 + hf * 8;
      *(float4*)(dst + 0) = make_float4(Areg[0], Areg[1], Areg[2], Areg[3]);
      *(float4*)(dst + 4) = make_float4(Areg[4], Areg[5], Areg[6], Areg[7]);
    }
  }
}

__global__ void __launch_bounds__(256) k_node_update(
    const float* __restrict__ Abuf, const float* __restrict__ featsOld,
    float* __restrict__ featsNew, const float* __restrict__ Wmix,
    const float* __restrict__ Wskip, const float* __restrict__ Wc,
    const float* __restrict__ Wout, const float* __restrict__ Wro,
    const int* __restrict__ species, const int* __restrict__ batch,
    const int* __restrict__ headArr, float* __restrict__ out) {
  __shared__ float Wmixs[C_CH * C_CH];
  __shared__ float Wouts[C_CH * C_CH];
  __shared__ __align__(16) float As[4 * C_CH * S_SPH];
  __shared__ float qs[4][C_CH];
  int tid = threadIdx.x;
  for (int i = tid; i < C_CH * C_CH; i += 256) {
    Wmixs[i] = Wmix[i];
    Wouts[i] = Wout[i];
  }
  size_t base = (size_t)blockIdx.x * 4 * C_CH * S_SPH;
  for (int i = tid; i < 4 * C_CH * S_SPH; i += 256) As[i] = Abuf[base + i];
  __syncthreads();
  int nl = tid >> 6, t = tid & 63;
  int node = blockIdx.x * 4 + nl;
  int sp = species[node];
  float A2[S_SPH];
#pragma unroll
  for (int s = 0; s < S_SPH; ++s) A2[s] = 0.0f;
  const float4* Ac = (const float4*)&As[nl * C_CH * S_SPH];
  for (int c = 0; c < C_CH; ++c) {
    float wm = Wmixs[c * C_CH + t];
    float4 v0 = Ac[c * 4 + 0], v1 = Ac[c * 4 + 1], v2 = Ac[c * 4 + 2], v3 = Ac[c * 4 + 3];
    A2[0] += wm * v0.x; A2[1] += wm * v0.y; A2[2] += wm * v0.z; A2[3] += wm * v0.w;
    A2[4] += wm * v1.x; A2[5] += wm * v1.y; A2[6] += wm * v1.z; A2[7] += wm * v1.w;
    A2[8] += wm * v2.x; A2[9] += wm * v2.y; A2[10] += wm * v2.z; A2[11] += wm * v2.w;
    A2[12] += wm * v3.x; A2[13] += wm * v3.y; A2[14] += wm * v3.z; A2[15] += wm * v3.w;
  }
  float p1 = A2[0];
  float p2 = 0.0f;
#pragma unroll
  for (int s = 0; s < S_SPH; ++s) p2 += A2[s] * A2[s];
  float p3 = p2 * p1;
  float q = Wc[(sp * 3 + 0) * C_CH + t] * p1 + Wc[(sp * 3 + 1) * C_CH + t] * p2 +
            Wc[(sp * 3 + 2) * C_CH + t] * p3;
  qs[nl][t] = q;
  float sc = 0.0f;
  for (int c = 0; c < C_CH; ++c)
    sc += featsOld[node * C_CH + c] * Wskip[(c * NE_EL + sp) * C_CH + t];
  __syncthreads();
  float nf = sc;
#pragma unroll
  for (int d = 0; d < C_CH; ++d) nf += qs[nl][d] * Wouts[d * C_CH + t];
  featsNew[node * C_CH + t] = nf;
  int b = batch[node];
  int h = headArr[b];
  float en = nf * Wro[t * N_HEADS + h];
#pragma unroll
  for (int off = 32; off; off >>= 1) en += __shfl_down(en, off, 64);
  if (t == 0) atomicAdd(&out[b], en);
}

extern "C" void kernel_launch(void* const* d_in, const int* in_sizes, int n_in,
                              void* d_out, int out_size, void* d_ws, size_t ws_size,
                              hipStream_t stream) {
  const float* pos = (const float*)d_in[0];
  const float* attrs = (const float*)d_in[1];
  const float* shifts = (const float*)d_in[2];
  const float* ae = (const float*)d_in[3];
  const float* Wemb = (const float*)d_in[4];
  const float* Wup = (const float*)d_in[5];
  const float* w1 = (const float*)d_in[6];
  const float* w2 = (const float*)d_in[7];
  const float* w3 = (const float*)d_in[8];
  const float* Wmix = (const float*)d_in[9];
  const float* Wskip = (const float*)d_in[10];
  const float* Wc = (const float*)d_in[11];
  const float* Wout = (const float*)d_in[12];
  const float* Wro = (const float*)d_in[13];
  const int* ei = (const int*)d_in[14];
  const int* batch = (const int*)d_in[15];
  const int* head = (const int*)d_in[16];
  float* out = (float*)d_out;

  char* p = (char*)d_ws;
  float* Yp = (float*)p;     p += (size_t)N_EDGES * 16 * 4;
  float* radp = (float*)p;   p += (size_t)N_EDGES * 8 * 4;
  float* up = (float*)p;     p += (size_t)N_NODES * 64 * 4;
  float* upe = (float*)p;    p += (size_t)N_EDGES * 64 * 4;
  float* fA = (float*)p;     p += (size_t)N_NODES * 64 * 4;
  float* fB = (float*)p;     p += (size_t)N_NODES * 64 * 4;
  float* Abuf = (float*)p;   p += (size_t)N_NODES * 1024 * 4;
  u16* h2 = (u16*)p;         p += (size_t)N_EDGES * 64 * 2;
  u16* W3T = (u16*)p;        p += (size_t)L_LAY * 65536 * 2;
  u16* w2T = (u16*)p;        p += (size_t)L_LAY * 4096 * 2;
  int* species = (int*)p;    p += (size_t)N_NODES * 4;
  int* deg = (int*)p;        p += (size_t)N_NODES * 4;
  int* rowptr = (int*)p;     p += (size_t)(N_NODES + 4) * 4;
  int* woff = (int*)p;       p += (size_t)N_NODES * 4;
  int* rank = (int*)p;       p += (size_t)N_EDGES * 4;
  int* sndp = (int*)p;       p += (size_t)N_EDGES * 4;
  if ((size_t)(p - (char*)d_ws) > ws_size) return;

  k_init0<<<(N_NODES + 255) / 256, 256, 0, stream>>>(out, deg);
  k_node_init<<<(N_NODES + 255) / 256, 256, 0, stream>>>(attrs, ae, batch, head, species, out);
  k_embed<<<(N_NODES * C_CH + 255) / 256, 256, 0, stream>>>(species, Wemb, fA);
  k_hist<<<(N_EDGES + 255) / 256, 256, 0, stream>>>(ei, deg);
  k_scan<<<1, 1024, 0, stream>>>(deg, rowptr, woff);
  k_permute<<<(N_EDGES + 255) / 256, 256, 0, stream>>>(ei, woff, rank, sndp);
  k_geom<<<(N_EDGES + 255) / 256, 256, 0, stream>>>(pos, shifts, ei, rank, Yp, radp);
  k_prep<<<(L_LAY * 65536 + L_LAY * 4096 + 255) / 256, 256, 0, stream>>>(w3, w2, W3T, w2T);

  const float* fOld = fA;
  float* fNew = fB;
  for (int l = 0; l < L_LAY; ++l) {
    k_edge_mlp<<<N_EDGES / 16, 64, 0, stream>>>(radp, w1 + l * NB_R * HID_D, w2T + l * 4096, h2);
    k_up<<<512, 256, 0, stream>>>(fOld, Wup + l * C_CH * C_CH, up);
    k_upe<<<2048, 256, 0, stream>>>(up, sndp, upe);
    k_gather<<<N_NODES / 4, 64, 0, stream>>>(h2, W3T + l * 65536, upe, Yp, rowptr, Abuf);
    k_node_update<<<N_NODES / 4, 256, 0, stream>>>(
        Abuf, fOld, fNew, Wmix + l * C_CH * C_CH, Wskip + l * C_CH * NE_EL * C_CH,
        Wc + l * NE_EL * 3 * C_CH, Wout + l * C_CH * C_CH, Wro + l * C_CH * N_HEADS,
        species, batch, head, out);
    const float* tmp = fNew;
    fNew = (float*)fOld;
    fOld = tmp;
  }
}

// Round 5
// 523.743 us; speedup vs baseline: 2.2275x; 1.0112x over previous
//
#include <hip/hip_runtime.h>

typedef unsigned short u16;
typedef unsigned int u32;
typedef __attribute__((ext_vector_type(8))) short short8;
typedef __attribute__((ext_vector_type(4))) float f32x4;

#define N_NODES 10000
#define N_EDGES 100000
#define C_CH 64
#define S_SPH 16
#define NB_R 8
#define HID_D 64
#define NE_EL 10
#define G_GR 64
#define L_LAY 2
#define N_HEADS 1
#define RCUT 5.0f
#define INV_AVG (1.0f/16.0f)

__device__ __forceinline__ u16 f2bf(float f) {
  u32 u = __float_as_uint(f);
  u32 r = (u + 0x7FFFu + ((u >> 16) & 1u)) >> 16;
  return (u16)r;
}

__global__ void k_init0(float* __restrict__ out, int* __restrict__ deg) {
  int i = blockIdx.x * 256 + threadIdx.x;
  if (i < G_GR) out[i] = 0.0f;
  if (i < N_NODES) deg[i] = 0;
}

__global__ void k_node_init(const float* __restrict__ attrs, const float* __restrict__ ae,
                            const int* __restrict__ batch, const int* __restrict__ head,
                            int* __restrict__ species, float* __restrict__ out) {
  int n = blockIdx.x * 256 + threadIdx.x;
  if (n >= N_NODES) return;
  int sp = 0;
#pragma unroll
  for (int e = 0; e < NE_EL; ++e)
    if (attrs[n * NE_EL + e] > 0.5f) sp = e;
  species[n] = sp;
  int b = batch[n];
  int h = head[b];
  atomicAdd(&out[b], ae[h * NE_EL + sp]);
}

__global__ void k_embed(const int* __restrict__ species, const float* __restrict__ Wemb,
                        float* __restrict__ feats) {
  int idx = blockIdx.x * 256 + threadIdx.x;
  if (idx >= N_NODES * C_CH) return;
  feats[idx] = Wemb[species[idx >> 6] * C_CH + (idx & 63)];
}

__global__ void k_hist(const int* __restrict__ ei, int* __restrict__ deg) {
  int e = blockIdx.x * 256 + threadIdx.x;
  if (e >= N_EDGES) return;
  atomicAdd(&deg[ei[N_EDGES + e]], 1);
}

__global__ void __launch_bounds__(1024) k_scan(const int* __restrict__ deg,
                                               int* __restrict__ rowptr,
                                               int* __restrict__ woff) {
  __shared__ int wsum[16];
  __shared__ int carry_s;
  int tid = threadIdx.x;
  int lane = tid & 63, w = tid >> 6;
  if (tid == 0) carry_s = 0;
  __syncthreads();
  for (int base = 0; base < N_NODES; base += 1024) {
    int i = base + tid;
    int v = (i < N_NODES) ? deg[i] : 0;
    int orig = v;
#pragma unroll
    for (int off = 1; off < 64; off <<= 1) {
      int n = __shfl_up(v, off, 64);
      if (lane >= off) v += n;
    }
    if (lane == 63) wsum[w] = v;
    __syncthreads();
    if (w == 0 && lane < 16) {
      int x = wsum[lane];
#pragma unroll
      for (int off = 1; off < 16; off <<= 1) {
        int n = __shfl_up(x, off, 16);
        if (lane >= off) x += n;
      }
      wsum[lane] = x;
    }
    __syncthreads();
    int waveoff = (w > 0) ? wsum[w - 1] : 0;
    int carry = carry_s;
    int excl = carry + waveoff + v - orig;
    if (i < N_NODES) {
      rowptr[i] = excl;
      woff[i] = excl;
    }
    int tot = wsum[15];
    __syncthreads();
    if (tid == 0) carry_s = carry + tot;
    __syncthreads();
  }
  if (tid == 0) rowptr[N_NODES] = carry_s;
}

__global__ void k_permute(const int* __restrict__ ei, int* __restrict__ woff,
                          int* __restrict__ rank, int* __restrict__ sndp) {
  int e = blockIdx.x * 256 + threadIdx.x;
  if (e >= N_EDGES) return;
  int rdst = ei[N_EDGES + e];
  int pos = atomicAdd(&woff[rdst], 1);
  rank[e] = pos;
  sndp[pos] = ei[e];
}

__global__ void k_geom(const float* __restrict__ pos, const float* __restrict__ shifts,
                       const int* __restrict__ ei, const int* __restrict__ rank,
                       float* __restrict__ Yp, float* __restrict__ radp) {
  int e = blockIdx.x * 256 + threadIdx.x;
  if (e >= N_EDGES) return;
  int s = ei[e], r = ei[N_EDGES + e];
  float dx = pos[r * 3 + 0] - pos[s * 3 + 0] + shifts[e * 3 + 0];
  float dy = pos[r * 3 + 1] - pos[s * 3 + 1] + shifts[e * 3 + 1];
  float dz = pos[r * 3 + 2] - pos[s * 3 + 2] + shifts[e * 3 + 2];
  float rr = sqrtf(dx * dx + dy * dy + dz * dz);
  rr = fmaxf(rr, 1e-12f);
  float inv = 1.0f / rr;
  float x = dx * inv, y = dy * inv, z = dz * inv;
  float xx = x * x, yy = y * y, zz = z * z;
  const float s3 = 1.73205080757f, s5 = 2.2360679775f, s15 = 3.87298334621f;
  const float c1 = 2.09165006634f, c2 = 10.2469507659f, c3 = 1.62018517461f;
  const float c4 = 1.32287565553f, c5 = 5.12347538298f;
  int rk = rank[e];
  float4* Yo = (float4*)(Yp + (size_t)rk * 16);
  Yo[0] = make_float4(1.0f, s3 * x, s3 * y, s3 * z);
  Yo[1] = make_float4(s15 * x * y, s15 * y * z, 0.5f * s5 * (3.0f * zz - 1.0f), s15 * x * z);
  Yo[2] = make_float4(0.5f * s15 * (xx - yy), c1 * y * (3.0f * xx - yy), c2 * x * y * z,
                      c3 * y * (5.0f * zz - 1.0f));
  Yo[3] = make_float4(c4 * z * (5.0f * zz - 3.0f), c3 * x * (5.0f * zz - 1.0f),
                      c5 * z * (xx - yy), c1 * x * (xx - 3.0f * yy));
  float t = rr * (1.0f / RCUT);
  float t2 = t * t;
  float t6 = t2 * t2 * t2;
  float fcut = 1.0f - 28.0f * t6 + 48.0f * t6 * t - 21.0f * t6 * t2;
  if (rr >= RCUT) fcut = 0.0f;
  float pref = 0.63245553203f * inv * fcut;
  float arg = 3.14159265359f * rr * (1.0f / RCUT);
  float sa, ca;
  __sincosf(arg, &sa, &ca);
  float twoc = 2.0f * ca;
  float sprev = 0.0f, scur = sa;
  float rv[8];
#pragma unroll
  for (int n = 0; n < 8; ++n) {
    rv[n] = pref * scur;
    float snext = twoc * scur - sprev;
    sprev = scur;
    scur = snext;
  }
  float4* Ro = (float4*)(radp + (size_t)rk * 8);
  Ro[0] = make_float4(rv[0], rv[1], rv[2], rv[3]);
  Ro[1] = make_float4(rv[4], rv[5], rv[6], rv[7]);
}

// W3T[l][s][c][k] bf16; w2T[l][t][j] bf16; WmixF = Wmix packed as MFMA B-fragments:
// WmixF[l][r] with r = dc*1024 + hf*512 + kg*128 + col*8 + j,
// value = bf16(Wmix[l][c = hf*32+kg*8+j][d = dc*16+col])
__global__ void k_prep(const float* __restrict__ w3, const float* __restrict__ w2,
                       const float* __restrict__ wmix, u16* __restrict__ w3t,
                       u16* __restrict__ w2t, u16* __restrict__ wmixf) {
  int idx = blockIdx.x * 256 + threadIdx.x;
  if (idx < L_LAY * 65536) {
    int l = idx >> 16;
    int r = idx & 65535;
    int k = r & 63;
    int c = (r >> 6) & 63;
    int s = r >> 12;
    w3t[idx] = f2bf(w3[(l * 64 + k) * 1024 + c * 16 + s]);
  } else if (idx < L_LAY * 65536 + L_LAY * 4096) {
    int i = idx - L_LAY * 65536;
    int l = i >> 12;
    int r = i & 4095;
    int t = r >> 6;
    int j = r & 63;
    w2t[l * 4096 + t * 64 + j] = f2bf(w2[(l * 64 + j) * 64 + t]);
  } else if (idx < L_LAY * 65536 + 2 * L_LAY * 4096) {
    int i = idx - L_LAY * 65536 - L_LAY * 4096;
    int l = i >> 12;
    int r = i & 4095;
    int j = r & 7;
    int col = (r >> 3) & 15;
    int kg = (r >> 7) & 3;
    int hf = (r >> 9) & 1;
    int dc = (r >> 10) & 3;
    int c = hf * 32 + kg * 8 + j;
    int d = dc * 16 + col;
    wmixf[l * 4096 + r] = f2bf(wmix[(l * 64 + c) * 64 + d]);
  }
}

// edge MLP, MFMA layer-2: 1 wave = 16 edges. h1 staged bf16 in LDS, XOR-swizzled.
__global__ void __launch_bounds__(64) k_edge_mlp(const float* __restrict__ radp,
                                                 const float* __restrict__ w1,
                                                 const u16* __restrict__ w2T,
                                                 u16* __restrict__ h2) {
  __shared__ float w1s[NB_R * HID_D];
  __shared__ __align__(16) u16 h1b[16 * 64];
  int lane = threadIdx.x;
  for (int i = lane; i < NB_R * HID_D; i += 64) w1s[i] = w1[i];
  int er = lane & 15, jg = lane >> 4;
  int eb = blockIdx.x * 16;
  int e = eb + er;
  float4 ra = *(const float4*)(radp + (size_t)e * 8);
  float4 rb = *(const float4*)(radp + (size_t)e * 8 + 4);
  float rv[8] = {ra.x, ra.y, ra.z, ra.w, rb.x, rb.y, rb.z, rb.w};
  u32* hb = (u32*)h1b;
#pragma unroll
  for (int jj = 0; jj < 16; jj += 2) {
    float p0 = 0.f, p1 = 0.f;
#pragma unroll
    for (int k = 0; k < 8; ++k) {
      p0 += rv[k] * w1s[k * 64 + jg * 16 + jj];
      p1 += rv[k] * w1s[k * 64 + jg * 16 + jj + 1];
    }
    p0 = p0 / (1.f + __expf(-p0));
    p1 = p1 / (1.f + __expf(-p1));
    u32 packed = (u32)f2bf(p0) | ((u32)f2bf(p1) << 16);
    int d = jg * 8 + (jj >> 1);
    hb[er * 32 + (d ^ ((er & 7) << 2))] = packed;
  }
  int row = er, kg = jg, col = er;
  const u32* hbr = (const u32*)h1b;
  short8 a0 = *(const short8*)&hbr[row * 32 + ((kg * 4) ^ ((row & 7) << 2))];
  short8 a1 = *(const short8*)&hbr[row * 32 + ((16 + kg * 4) ^ ((row & 7) << 2))];
#pragma unroll
  for (int ch = 0; ch < 4; ++ch) {
    const u16* wp = w2T + (ch * 16 + col) * 64 + kg * 8;
    short8 b0 = *(const short8*)wp;
    short8 b1 = *(const short8*)(wp + 32);
    f32x4 acc = {0.f, 0.f, 0.f, 0.f};
    acc = __builtin_amdgcn_mfma_f32_16x16x32_bf16(a0, b0, acc, 0, 0, 0);
    acc = __builtin_amdgcn_mfma_f32_16x16x32_bf16(a1, b1, acc, 0, 0, 0);
#pragma unroll
    for (int rr = 0; rr < 4; ++rr) {
      float v = acc[rr];
      v = v / (1.f + __expf(-v));
      h2[(size_t)(eb + kg * 4 + rr) * 64 + ch * 16 + col] = f2bf(v);
    }
  }
}

// up = feats @ W_up * INV_AVG (node buffer)
__global__ void __launch_bounds__(256) k_up(const float* __restrict__ feats,
                                            const float* __restrict__ Wup,
                                            float* __restrict__ up) {
  __shared__ float ws[C_CH * C_CH];
  __shared__ float fs[4][C_CH];
  int tid = threadIdx.x;
  for (int i = tid; i < C_CH * C_CH; i += 256) ws[i] = Wup[i];
  __syncthreads();
  int slot = tid >> 6, t = tid & 63;
  for (int nb = blockIdx.x * 4; nb < N_NODES; nb += gridDim.x * 4) {
    int n = nb + slot;
    fs[slot][t] = feats[n * C_CH + t];
    float acc = 0.0f;
#pragma unroll
    for (int j = 0; j < C_CH; ++j) acc += fs[slot][j] * ws[j * C_CH + t];
    up[n * C_CH + t] = acc * INV_AVG;
  }
}

// upe[pos][c] = up[sndp[pos]][c]
__global__ void __launch_bounds__(256) k_upe(const float* __restrict__ up,
                                             const int* __restrict__ sndp,
                                             float* __restrict__ upe) {
  int tid = threadIdx.x;
  int slot = tid >> 6, t = tid & 63;
  for (int pb = blockIdx.x * 4; pb < N_EDGES; pb += gridDim.x * 4) {
    int pos = pb + slot;
    upe[(size_t)pos * 64 + t] = up[(size_t)sndp[pos] * 64 + t];
  }
}

// Gather: 1 wave per block, 4 nodes per wave, B-fragments in registers.
__global__ void __launch_bounds__(64) k_gather(const u16* __restrict__ h2,
                                               const u16* __restrict__ W3T,
                                               const float* __restrict__ upe,
                                               const float* __restrict__ Yp,
                                               const int* __restrict__ rowptr,
                                               float* __restrict__ Abuf) {
  __shared__ __align__(16) float Yt[16][20];
  int lane = threadIdx.x;
  int row = lane & 15, kg = lane >> 4;
  int col = row;
  int nb = blockIdx.x * 4;
  int rp0 = rowptr[nb], rp1 = rowptr[nb + 1], rp2 = rowptr[nb + 2], rp3 = rowptr[nb + 3],
      rp4 = rowptr[nb + 4];
  int d0 = rp1 - rp0, d1 = rp2 - rp1, d2 = rp3 - rp2, d3 = rp4 - rp3;
  int rmax = max(max((d0 + 3) >> 2, (d1 + 3) >> 2), max((d2 + 3) >> 2, (d3 + 3) >> 2));
  rmax = max(rmax, 1);
  int nr = row >> 2;
  int baseA = nr == 0 ? rp0 : nr == 1 ? rp1 : nr == 2 ? rp2 : rp3;
  int degA = nr == 0 ? d0 : nr == 1 ? d1 : nr == 2 ? d2 : d3;
  int baseR = kg == 0 ? rp0 : kg == 1 ? rp1 : kg == 2 ? rp2 : rp3;
  int degR = kg == 0 ? d0 : kg == 1 ? d1 : kg == 2 ? d2 : d3;
  int nodeR = nb + kg;

#pragma unroll 1
  for (int cg = 0; cg < 4; ++cg) {
#pragma unroll 1
    for (int hf = 0; hf < 2; ++hf) {
      short8 B0[8], B1[8];
#pragma unroll
      for (int ss = 0; ss < 8; ++ss) {
        int s = hf * 8 + ss;
        const u16* wp = W3T + (((s * 64 + cg * 16 + col) << 6) + kg * 8);
        B0[ss] = *(const short8*)wp;
        B1[ss] = *(const short8*)(wp + 32);
      }
      float Areg[8];
#pragma unroll
      for (int ss = 0; ss < 8; ++ss) Areg[ss] = 0.f;
#pragma unroll 1
      for (int r = 0; r < rmax; ++r) {
        int sl = r * 4 + (row & 3);
        short8 a0 = {0, 0, 0, 0, 0, 0, 0, 0};
        short8 a1 = {0, 0, 0, 0, 0, 0, 0, 0};
        float4 yq = make_float4(0.f, 0.f, 0.f, 0.f);
        if (sl < degA) {
          int eA = baseA + sl;
          a0 = *(const short8*)(h2 + (size_t)eA * 64 + kg * 8);
          a1 = *(const short8*)(h2 + (size_t)eA * 64 + 32 + kg * 8);
          yq = *(const float4*)(Yp + (size_t)eA * 16 + kg * 4);
        }
        Yt[kg * 4 + 0][row] = yq.x;
        Yt[kg * 4 + 1][row] = yq.y;
        Yt[kg * 4 + 2][row] = yq.z;
        Yt[kg * 4 + 3][row] = yq.w;
        float upv[4];
#pragma unroll
        for (int q = 0; q < 4; ++q) {
          int slq = r * 4 + q;
          int pos = (slq < degR) ? (baseR + slq) : 0;
          float u = upe[(size_t)pos * 64 + cg * 16 + col];
          upv[q] = (slq < degR) ? u : 0.f;
        }
#pragma unroll
        for (int ss = 0; ss < 8; ++ss) {
          f32x4 acc = {0.f, 0.f, 0.f, 0.f};
          acc = __builtin_amdgcn_mfma_f32_16x16x32_bf16(a0, B0[ss], acc, 0, 0, 0);
          acc = __builtin_amdgcn_mfma_f32_16x16x32_bf16(a1, B1[ss], acc, 0, 0, 0);
          float4 yv = *(const float4*)&Yt[hf * 8 + ss][kg * 4];
          Areg[ss] += acc[0] * yv.x * upv[0] + acc[1] * yv.y * upv[1] + acc[2] * yv.z * upv[2] +
                      acc[3] * yv.w * upv[3];
        }
      }
      float* dst = Abuf + (size_t)nodeR * 1024 + (cg * 16 + col) * 16 + hf * 8;
      *(float4*)(dst + 0) = make_float4(Areg[0], Areg[1], Areg[2], Areg[3]);
      *(float4*)(dst + 4) = make_float4(Areg[4], Areg[5], Areg[6], Areg[7]);
    }
  }
}

// Node update v2: wave = 1 node. Mix via 8 MFMA (Wmix fragments in VGPR),
// p1/p2 via shfl reductions, skip/Wout stay vector (128 FMA/thread).
__global__ void __launch_bounds__(256) k_node_update(
    const float* __restrict__ Abuf, const float* __restrict__ featsOld,
    float* __restrict__ featsNew, const u16* __restrict__ WmixF,
    const float* __restrict__ Wskip, const float* __restrict__ Wc,
    const float* __restrict__ Wout, const float* __restrict__ Wro,
    const int* __restrict__ species, const int* __restrict__ batch,
    const int* __restrict__ headArr, float* __restrict__ out) {
  __shared__ float Wouts[C_CH * C_CH];
  __shared__ float qs[4][C_CH];
  int tid = threadIdx.x;
  for (int i = tid; i < C_CH * C_CH; i += 256) Wouts[i] = Wout[i];
  int nl = tid >> 6, lane = tid & 63;
  int row = lane & 15, kg = lane >> 4;
  int node = blockIdx.x * 4 + nl;
  int sp = species[node];
  // Wmix B-fragments (bf16, packed by k_prep): [dchunk][half]
  short8 WF[4][2];
#pragma unroll
  for (int dc = 0; dc < 4; ++dc)
#pragma unroll
    for (int hf = 0; hf < 2; ++hf)
      WF[dc][hf] = *(const short8*)(WmixF + (size_t)(dc * 1024 + hf * 512 + kg * 128 + row * 8));
  // A-fragment: A[c][s] with s=row, c=kg*8+j (+32)
  const float* Arow = Abuf + (size_t)node * 1024;
  short8 a0, a1;
#pragma unroll
  for (int j = 0; j < 8; ++j) {
    a0[j] = (short)f2bf(Arow[(kg * 8 + j) * 16 + row]);
    a1[j] = (short)f2bf(Arow[(32 + kg * 8 + j) * 16 + row]);
  }
#pragma unroll
  for (int dc = 0; dc < 4; ++dc) {
    f32x4 acc = {0.f, 0.f, 0.f, 0.f};
    acc = __builtin_amdgcn_mfma_f32_16x16x32_bf16(a0, WF[dc][0], acc, 0, 0, 0);
    acc = __builtin_amdgcn_mfma_f32_16x16x32_bf16(a1, WF[dc][1], acc, 0, 0, 0);
    // acc[r] = A2[s = kg*4+r][d = dc*16+row]
    float psq = acc[0] * acc[0] + acc[1] * acc[1] + acc[2] * acc[2] + acc[3] * acc[3];
    psq += __shfl_xor(psq, 16, 64);
    psq += __shfl_xor(psq, 32, 64);             // p2[d]
    float p1 = __shfl(acc[0], lane & 15, 64);   // A2[s=0][d] from kg=0 lane
    float p3 = psq * p1;
    int d = dc * 16 + row;
    float qv = Wc[(sp * 3 + 0) * 64 + d] * p1 + Wc[(sp * 3 + 1) * 64 + d] * psq +
               Wc[(sp * 3 + 2) * 64 + d] * p3;
    if (kg == 0) qs[nl][d] = qv;
  }
  __syncthreads();
  int t = lane;
  const float* frow = featsOld + (size_t)node * 64;
  float sc = 0.0f;
#pragma unroll 8
  for (int c = 0; c < 64; ++c) sc += frow[c] * Wskip[(c * NE_EL + sp) * 64 + t];
  float nf = sc;
#pragma unroll 8
  for (int d = 0; d < 64; ++d) nf += qs[nl][d] * Wouts[d * 64 + t];
  featsNew[(size_t)node * 64 + t] = nf;
  int b = batch[node];
  int h = headArr[b];
  float en = nf * Wro[t * N_HEADS + h];
#pragma unroll
  for (int off = 32; off; off >>= 1) en += __shfl_down(en, off, 64);
  if (t == 0) atomicAdd(&out[b], en);
}

extern "C" void kernel_launch(void* const* d_in, const int* in_sizes, int n_in,
                              void* d_out, int out_size, void* d_ws, size_t ws_size,
                              hipStream_t stream) {
  const float* pos = (const float*)d_in[0];
  const float* attrs = (const float*)d_in[1];
  const float* shifts = (const float*)d_in[2];
  const float* ae = (const float*)d_in[3];
  const float* Wemb = (const float*)d_in[4];
  const float* Wup = (const float*)d_in[5];
  const float* w1 = (const float*)d_in[6];
  const float* w2 = (const float*)d_in[7];
  const float* w3 = (const float*)d_in[8];
  const float* Wmix = (const float*)d_in[9];
  const float* Wskip = (const float*)d_in[10];
  const float* Wc = (const float*)d_in[11];
  const float* Wout = (const float*)d_in[12];
  const float* Wro = (const float*)d_in[13];
  const int* ei = (const int*)d_in[14];
  const int* batch = (const int*)d_in[15];
  const int* head = (const int*)d_in[16];
  float* out = (float*)d_out;

  char* p = (char*)d_ws;
  float* Yp = (float*)p;     p += (size_t)N_EDGES * 16 * 4;
  float* radp = (float*)p;   p += (size_t)N_EDGES * 8 * 4;
  float* up = (float*)p;     p += (size_t)N_NODES * 64 * 4;
  float* upe = (float*)p;    p += (size_t)N_EDGES * 64 * 4;
  float* fA = (float*)p;     p += (size_t)N_NODES * 64 * 4;
  float* fB = (float*)p;     p += (size_t)N_NODES * 64 * 4;
  float* Abuf = (float*)p;   p += (size_t)N_NODES * 1024 * 4;
  u16* h2 = (u16*)p;         p += (size_t)N_EDGES * 64 * 2;
  u16* W3T = (u16*)p;        p += (size_t)L_LAY * 65536 * 2;
  u16* w2T = (u16*)p;        p += (size_t)L_LAY * 4096 * 2;
  u16* WmixF = (u16*)p;      p += (size_t)L_LAY * 4096 * 2;
  int* species = (int*)p;    p += (size_t)N_NODES * 4;
  int* deg = (int*)p;        p += (size_t)N_NODES * 4;
  int* rowptr = (int*)p;     p += (size_t)(N_NODES + 4) * 4;
  int* woff = (int*)p;       p += (size_t)N_NODES * 4;
  int* rank = (int*)p;       p += (size_t)N_EDGES * 4;
  int* sndp = (int*)p;       p += (size_t)N_EDGES * 4;
  if ((size_t)(p - (char*)d_ws) > ws_size) return;

  k_init0<<<(N_NODES + 255) / 256, 256, 0, stream>>>(out, deg);
  k_node_init<<<(N_NODES + 255) / 256, 256, 0, stream>>>(attrs, ae, batch, head, species, out);
  k_embed<<<(N_NODES * C_CH + 255) / 256, 256, 0, stream>>>(species, Wemb, fA);
  k_hist<<<(N_EDGES + 255) / 256, 256, 0, stream>>>(ei, deg);
  k_scan<<<1, 1024, 0, stream>>>(deg, rowptr, woff);
  k_permute<<<(N_EDGES + 255) / 256, 256, 0, stream>>>(ei, woff, rank, sndp);
  k_geom<<<(N_EDGES + 255) / 256, 256, 0, stream>>>(pos, shifts, ei, rank, Yp, radp);
  k_prep<<<(L_LAY * 65536 + 2 * L_LAY * 4096 + 255) / 256, 256, 0, stream>>>(w3, w2, Wmix, W3T,
                                                                             w2T, WmixF);

  const float* fOld = fA;
  float* fNew = fB;
  for (int l = 0; l < L_LAY; ++l) {
    k_edge_mlp<<<N_EDGES / 16, 64, 0, stream>>>(radp, w1 + l * NB_R * HID_D, w2T + l * 4096, h2);
    k_up<<<512, 256, 0, stream>>>(fOld, Wup + l * C_CH * C_CH, up);
    k_upe<<<2048, 256, 0, stream>>>(up, sndp, upe);
    k_gather<<<N_NODES / 4, 64, 0, stream>>>(h2, W3T + l * 65536, upe, Yp, rowptr, Abuf);
    k_node_update<<<N_NODES / 4, 256, 0, stream>>>(
        Abuf, fOld, fNew, WmixF + l * 4096, Wskip + l * C_CH * NE_EL * C_CH,
        Wc + l * NE_EL * 3 * C_CH, Wout + l * C_CH * C_CH, Wro + l * C_CH * N_HEADS,
        species, batch, head, out);
    const float* tmp = fNew;
    fNew = (float*)fOld;
    fOld = tmp;
  }
}

// Round 6
// 505.113 us; speedup vs baseline: 2.3096x; 1.0369x over previous
//
#include <hip/hip_runtime.h>

typedef unsigned short u16;
typedef unsigned int u32;
typedef __attribute__((ext_vector_type(8))) short short8;
typedef __attribute__((ext_vector_type(4))) float f32x4;

#define N_NODES 10000
#define N_EDGES 100000
#define C_CH 64
#define S_SPH 16
#define NB_R 8
#define HID_D 64
#define NE_EL 10
#define G_GR 64
#define L_LAY 2
#define N_HEADS 1
#define RCUT 5.0f
#define INV_AVG (1.0f/16.0f)

__device__ __forceinline__ u16 f2bf(float f) {
  u32 u = __float_as_uint(f);
  u32 r = (u + 0x7FFFu + ((u >> 16) & 1u)) >> 16;
  return (u16)r;
}

__global__ void k_init0(float* __restrict__ out, int* __restrict__ deg) {
  int i = blockIdx.x * 256 + threadIdx.x;
  if (i < G_GR) out[i] = 0.0f;
  if (i < N_NODES) deg[i] = 0;
}

__global__ void k_node_init(const float* __restrict__ attrs, const float* __restrict__ ae,
                            const int* __restrict__ batch, const int* __restrict__ head,
                            int* __restrict__ species, float* __restrict__ out) {
  int n = blockIdx.x * 256 + threadIdx.x;
  if (n >= N_NODES) return;
  int sp = 0;
#pragma unroll
  for (int e = 0; e < NE_EL; ++e)
    if (attrs[n * NE_EL + e] > 0.5f) sp = e;
  species[n] = sp;
  int b = batch[n];
  int h = head[b];
  atomicAdd(&out[b], ae[h * NE_EL + sp]);
}

__global__ void k_embed(const int* __restrict__ species, const float* __restrict__ Wemb,
                        float* __restrict__ feats) {
  int idx = blockIdx.x * 256 + threadIdx.x;
  if (idx >= N_NODES * C_CH) return;
  feats[idx] = Wemb[species[idx >> 6] * C_CH + (idx & 63)];
}

__global__ void k_hist(const int* __restrict__ ei, int* __restrict__ deg) {
  int e = blockIdx.x * 256 + threadIdx.x;
  if (e >= N_EDGES) return;
  atomicAdd(&deg[ei[N_EDGES + e]], 1);
}

__global__ void __launch_bounds__(1024) k_scan(const int* __restrict__ deg,
                                               int* __restrict__ rowptr,
                                               int* __restrict__ woff) {
  __shared__ int wsum[16];
  __shared__ int carry_s;
  int tid = threadIdx.x;
  int lane = tid & 63, w = tid >> 6;
  if (tid == 0) carry_s = 0;
  __syncthreads();
  for (int base = 0; base < N_NODES; base += 1024) {
    int i = base + tid;
    int v = (i < N_NODES) ? deg[i] : 0;
    int orig = v;
#pragma unroll
    for (int off = 1; off < 64; off <<= 1) {
      int n = __shfl_up(v, off, 64);
      if (lane >= off) v += n;
    }
    if (lane == 63) wsum[w] = v;
    __syncthreads();
    if (w == 0 && lane < 16) {
      int x = wsum[lane];
#pragma unroll
      for (int off = 1; off < 16; off <<= 1) {
        int n = __shfl_up(x, off, 16);
        if (lane >= off) x += n;
      }
      wsum[lane] = x;
    }
    __syncthreads();
    int waveoff = (w > 0) ? wsum[w - 1] : 0;
    int carry = carry_s;
    int excl = carry + waveoff + v - orig;
    if (i < N_NODES) {
      rowptr[i] = excl;
      woff[i] = excl;
    }
    int tot = wsum[15];
    __syncthreads();
    if (tid == 0) carry_s = carry + tot;
    __syncthreads();
  }
  if (tid == 0) rowptr[N_NODES] = carry_s;
}

__global__ void k_permute(const int* __restrict__ ei, int* __restrict__ woff,
                          int* __restrict__ rank, int* __restrict__ sndp) {
  int e = blockIdx.x * 256 + threadIdx.x;
  if (e >= N_EDGES) return;
  int rdst = ei[N_EDGES + e];
  int pos = atomicAdd(&woff[rdst], 1);
  rank[e] = pos;
  sndp[pos] = ei[e];
}

__global__ void k_geom(const float* __restrict__ pos, const float* __restrict__ shifts,
                       const int* __restrict__ ei, const int* __restrict__ rank,
                       float* __restrict__ Yp, float* __restrict__ radp) {
  int e = blockIdx.x * 256 + threadIdx.x;
  if (e >= N_EDGES) return;
  int s = ei[e], r = ei[N_EDGES + e];
  float dx = pos[r * 3 + 0] - pos[s * 3 + 0] + shifts[e * 3 + 0];
  float dy = pos[r * 3 + 1] - pos[s * 3 + 1] + shifts[e * 3 + 1];
  float dz = pos[r * 3 + 2] - pos[s * 3 + 2] + shifts[e * 3 + 2];
  float rr = sqrtf(dx * dx + dy * dy + dz * dz);
  rr = fmaxf(rr, 1e-12f);
  float inv = 1.0f / rr;
  float x = dx * inv, y = dy * inv, z = dz * inv;
  float xx = x * x, yy = y * y, zz = z * z;
  const float s3 = 1.73205080757f, s5 = 2.2360679775f, s15 = 3.87298334621f;
  const float c1 = 2.09165006634f, c2 = 10.2469507659f, c3 = 1.62018517461f;
  const float c4 = 1.32287565553f, c5 = 5.12347538298f;
  int rk = rank[e];
  float4* Yo = (float4*)(Yp + (size_t)rk * 16);
  Yo[0] = make_float4(1.0f, s3 * x, s3 * y, s3 * z);
  Yo[1] = make_float4(s15 * x * y, s15 * y * z, 0.5f * s5 * (3.0f * zz - 1.0f), s15 * x * z);
  Yo[2] = make_float4(0.5f * s15 * (xx - yy), c1 * y * (3.0f * xx - yy), c2 * x * y * z,
                      c3 * y * (5.0f * zz - 1.0f));
  Yo[3] = make_float4(c4 * z * (5.0f * zz - 3.0f), c3 * x * (5.0f * zz - 1.0f),
                      c5 * z * (xx - yy), c1 * x * (xx - 3.0f * yy));
  float t = rr * (1.0f / RCUT);
  float t2 = t * t;
  float t6 = t2 * t2 * t2;
  float fcut = 1.0f - 28.0f * t6 + 48.0f * t6 * t - 21.0f * t6 * t2;
  if (rr >= RCUT) fcut = 0.0f;
  float pref = 0.63245553203f * inv * fcut;
  float arg = 3.14159265359f * rr * (1.0f / RCUT);
  float sa, ca;
  __sincosf(arg, &sa, &ca);
  float twoc = 2.0f * ca;
  float sprev = 0.0f, scur = sa;
  float rv[8];
#pragma unroll
  for (int n = 0; n < 8; ++n) {
    rv[n] = pref * scur;
    float snext = twoc * scur - sprev;
    sprev = scur;
    scur = snext;
  }
  float4* Ro = (float4*)(radp + (size_t)rk * 8);
  Ro[0] = make_float4(rv[0], rv[1], rv[2], rv[3]);
  Ro[1] = make_float4(rv[4], rv[5], rv[6], rv[7]);
}

// W3T[l][s][c][k] bf16; w2T[l][t][j] bf16; WmixF = Wmix packed as MFMA B-fragments
__global__ void k_prep(const float* __restrict__ w3, const float* __restrict__ w2,
                       const float* __restrict__ wmix, u16* __restrict__ w3t,
                       u16* __restrict__ w2t, u16* __restrict__ wmixf) {
  int idx = blockIdx.x * 256 + threadIdx.x;
  if (idx < L_LAY * 65536) {
    int l = idx >> 16;
    int r = idx & 65535;
    int k = r & 63;
    int c = (r >> 6) & 63;
    int s = r >> 12;
    w3t[idx] = f2bf(w3[(l * 64 + k) * 1024 + c * 16 + s]);
  } else if (idx < L_LAY * 65536 + L_LAY * 4096) {
    int i = idx - L_LAY * 65536;
    int l = i >> 12;
    int r = i & 4095;
    int t = r >> 6;
    int j = r & 63;
    w2t[l * 4096 + t * 64 + j] = f2bf(w2[(l * 64 + j) * 64 + t]);
  } else if (idx < L_LAY * 65536 + 2 * L_LAY * 4096) {
    int i = idx - L_LAY * 65536 - L_LAY * 4096;
    int l = i >> 12;
    int r = i & 4095;
    int j = r & 7;
    int col = (r >> 3) & 15;
    int kg = (r >> 7) & 3;
    int hf = (r >> 9) & 1;
    int dc = (r >> 10) & 3;
    int c = hf * 32 + kg * 8 + j;
    int d = dc * 16 + col;
    wmixf[l * 4096 + r] = f2bf(wmix[(l * 64 + c) * 64 + d]);
  }
}

// edge MLP, MFMA layer-2: 1 wave = 16 edges. h1 staged bf16 in LDS, XOR-swizzled.
__global__ void __launch_bounds__(64) k_edge_mlp(const float* __restrict__ radp,
                                                 const float* __restrict__ w1,
                                                 const u16* __restrict__ w2T,
                                                 u16* __restrict__ h2) {
  __shared__ float w1s[NB_R * HID_D];
  __shared__ __align__(16) u16 h1b[16 * 64];
  int lane = threadIdx.x;
  for (int i = lane; i < NB_R * HID_D; i += 64) w1s[i] = w1[i];
  int er = lane & 15, jg = lane >> 4;
  int eb = blockIdx.x * 16;
  int e = eb + er;
  float4 ra = *(const float4*)(radp + (size_t)e * 8);
  float4 rb = *(const float4*)(radp + (size_t)e * 8 + 4);
  float rv[8] = {ra.x, ra.y, ra.z, ra.w, rb.x, rb.y, rb.z, rb.w};
  u32* hb = (u32*)h1b;
#pragma unroll
  for (int jj = 0; jj < 16; jj += 2) {
    float p0 = 0.f, p1 = 0.f;
#pragma unroll
    for (int k = 0; k < 8; ++k) {
      p0 += rv[k] * w1s[k * 64 + jg * 16 + jj];
      p1 += rv[k] * w1s[k * 64 + jg * 16 + jj + 1];
    }
    p0 = p0 / (1.f + __expf(-p0));
    p1 = p1 / (1.f + __expf(-p1));
    u32 packed = (u32)f2bf(p0) | ((u32)f2bf(p1) << 16);
    int d = jg * 8 + (jj >> 1);
    hb[er * 32 + (d ^ ((er & 7) << 2))] = packed;
  }
  int row = er, kg = jg, col = er;
  const u32* hbr = (const u32*)h1b;
  short8 a0 = *(const short8*)&hbr[row * 32 + ((kg * 4) ^ ((row & 7) << 2))];
  short8 a1 = *(const short8*)&hbr[row * 32 + ((16 + kg * 4) ^ ((row & 7) << 2))];
#pragma unroll
  for (int ch = 0; ch < 4; ++ch) {
    const u16* wp = w2T + (ch * 16 + col) * 64 + kg * 8;
    short8 b0 = *(const short8*)wp;
    short8 b1 = *(const short8*)(wp + 32);
    f32x4 acc = {0.f, 0.f, 0.f, 0.f};
    acc = __builtin_amdgcn_mfma_f32_16x16x32_bf16(a0, b0, acc, 0, 0, 0);
    acc = __builtin_amdgcn_mfma_f32_16x16x32_bf16(a1, b1, acc, 0, 0, 0);
#pragma unroll
    for (int rr = 0; rr < 4; ++rr) {
      float v = acc[rr];
      v = v / (1.f + __expf(-v));
      h2[(size_t)(eb + kg * 4 + rr) * 64 + ch * 16 + col] = f2bf(v);
    }
  }
}

// up = feats @ W_up * INV_AVG
__global__ void __launch_bounds__(256) k_up(const float* __restrict__ feats,
                                            const float* __restrict__ Wup,
                                            float* __restrict__ up) {
  __shared__ float ws[C_CH * C_CH];
  __shared__ float fs[4][C_CH];
  int tid = threadIdx.x;
  for (int i = tid; i < C_CH * C_CH; i += 256) ws[i] = Wup[i];
  __syncthreads();
  int slot = tid >> 6, t = tid & 63;
  for (int nb = blockIdx.x * 4; nb < N_NODES; nb += gridDim.x * 4) {
    int n = nb + slot;
    fs[slot][t] = feats[n * C_CH + t];
    float acc = 0.0f;
#pragma unroll
    for (int j = 0; j < C_CH; ++j) acc += fs[slot][j] * ws[j * C_CH + t];
    up[n * C_CH + t] = acc * INV_AVG;
  }
}

// upe[pos][c] = up[sndp[pos]][c]
__global__ void __launch_bounds__(256) k_upe(const float* __restrict__ up,
                                             const int* __restrict__ sndp,
                                             float* __restrict__ upe) {
  int tid = threadIdx.x;
  int slot = tid >> 6, t = tid & 63;
  for (int pb = blockIdx.x * 4; pb < N_EDGES; pb += gridDim.x * 4) {
    int pos = pb + slot;
    upe[(size_t)pos * 64 + t] = up[(size_t)sndp[pos] * 64 + t];
  }
}

// Gather: 1 wave per block, 4 nodes per wave, B-fragments in registers.
// Output AbufB is bf16 in [n][s][c] layout (MFMA-A-fragment-ready for node_update).
__global__ void __launch_bounds__(64) k_gather(const u16* __restrict__ h2,
                                               const u16* __restrict__ W3T,
                                               const float* __restrict__ upe,
                                               const float* __restrict__ Yp,
                                               const int* __restrict__ rowptr,
                                               u16* __restrict__ AbufB) {
  __shared__ __align__(16) float Yt[16][20];
  int lane = threadIdx.x;
  int row = lane & 15, kg = lane >> 4;
  int col = row;
  int nb = blockIdx.x * 4;
  int rp0 = rowptr[nb], rp1 = rowptr[nb + 1], rp2 = rowptr[nb + 2], rp3 = rowptr[nb + 3],
      rp4 = rowptr[nb + 4];
  int d0 = rp1 - rp0, d1 = rp2 - rp1, d2 = rp3 - rp2, d3 = rp4 - rp3;
  int rmax = max(max((d0 + 3) >> 2, (d1 + 3) >> 2), max((d2 + 3) >> 2, (d3 + 3) >> 2));
  rmax = max(rmax, 1);
  int nr = row >> 2;
  int baseA = nr == 0 ? rp0 : nr == 1 ? rp1 : nr == 2 ? rp2 : rp3;
  int degA = nr == 0 ? d0 : nr == 1 ? d1 : nr == 2 ? d2 : d3;
  int baseR = kg == 0 ? rp0 : kg == 1 ? rp1 : kg == 2 ? rp2 : rp3;
  int degR = kg == 0 ? d0 : kg == 1 ? d1 : kg == 2 ? d2 : d3;
  int nodeR = nb + kg;

#pragma unroll 1
  for (int cg = 0; cg < 4; ++cg) {
#pragma unroll 1
    for (int hf = 0; hf < 2; ++hf) {
      short8 B0[8], B1[8];
#pragma unroll
      for (int ss = 0; ss < 8; ++ss) {
        int s = hf * 8 + ss;
        const u16* wp = W3T + (((s * 64 + cg * 16 + col) << 6) + kg * 8);
        B0[ss] = *(const short8*)wp;
        B1[ss] = *(const short8*)(wp + 32);
      }
      float Areg[8];
#pragma unroll
      for (int ss = 0; ss < 8; ++ss) Areg[ss] = 0.f;
#pragma unroll 1
      for (int r = 0; r < rmax; ++r) {
        int sl = r * 4 + (row & 3);
        short8 a0 = {0, 0, 0, 0, 0, 0, 0, 0};
        short8 a1 = {0, 0, 0, 0, 0, 0, 0, 0};
        float4 yq = make_float4(0.f, 0.f, 0.f, 0.f);
        if (sl < degA) {
          int eA = baseA + sl;
          a0 = *(const short8*)(h2 + (size_t)eA * 64 + kg * 8);
          a1 = *(const short8*)(h2 + (size_t)eA * 64 + 32 + kg * 8);
          yq = *(const float4*)(Yp + (size_t)eA * 16 + kg * 4);
        }
        Yt[kg * 4 + 0][row] = yq.x;
        Yt[kg * 4 + 1][row] = yq.y;
        Yt[kg * 4 + 2][row] = yq.z;
        Yt[kg * 4 + 3][row] = yq.w;
        float upv[4];
#pragma unroll
        for (int q = 0; q < 4; ++q) {
          int slq = r * 4 + q;
          int pos = (slq < degR) ? (baseR + slq) : 0;
          float u = upe[(size_t)pos * 64 + cg * 16 + col];
          upv[q] = (slq < degR) ? u : 0.f;
        }
#pragma unroll
        for (int ss = 0; ss < 8; ++ss) {
          f32x4 acc = {0.f, 0.f, 0.f, 0.f};
          acc = __builtin_amdgcn_mfma_f32_16x16x32_bf16(a0, B0[ss], acc, 0, 0, 0);
          acc = __builtin_amdgcn_mfma_f32_16x16x32_bf16(a1, B1[ss], acc, 0, 0, 0);
          float4 yv = *(const float4*)&Yt[hf * 8 + ss][kg * 4];
          Areg[ss] += acc[0] * yv.x * upv[0] + acc[1] * yv.y * upv[1] + acc[2] * yv.z * upv[2] +
                      acc[3] * yv.w * upv[3];
        }
      }
      u16* dst = AbufB + (size_t)nodeR * 1024 + (size_t)(hf * 8) * 64 + (cg * 16 + col);
#pragma unroll
      for (int ss = 0; ss < 8; ++ss) dst[ss * 64] = f2bf(Areg[ss]);
    }
  }
}

// Node update v3: wave = 2 nodes (block 256 = 8 nodes). A-frags = 2x dwordx4 bf16 loads.
__global__ void __launch_bounds__(256) k_node_update(
    const u16* __restrict__ AbufB, const float* __restrict__ featsOld,
    float* __restrict__ featsNew, const u16* __restrict__ WmixF,
    const float* __restrict__ Wskip, const float* __restrict__ Wc,
    const float* __restrict__ Wout, const float* __restrict__ Wro,
    const int* __restrict__ species, const int* __restrict__ batch,
    const int* __restrict__ headArr, float* __restrict__ out) {
  __shared__ float Wouts[C_CH * C_CH];
  __shared__ float qs[8][C_CH];
  int tid = threadIdx.x;
  for (int i = tid; i < C_CH * C_CH; i += 256) Wouts[i] = Wout[i];
  int nl = tid >> 6, lane = tid & 63;
  int row = lane & 15, kg = lane >> 4;
  int base = blockIdx.x * 8 + nl * 2;
  int sp0 = species[base], sp1 = species[base + 1];
  short8 WF[4][2];
#pragma unroll
  for (int dc = 0; dc < 4; ++dc)
#pragma unroll
    for (int hf = 0; hf < 2; ++hf)
      WF[dc][hf] = *(const short8*)(WmixF + (size_t)(dc * 1024 + hf * 512 + kg * 128 + row * 8));
  // A-fragments for both nodes: bf16 [n][s][c], s=row, c=kg*8+j (+32)
  const u16* Ar0 = AbufB + (size_t)base * 1024;
  const u16* Ar1 = Ar0 + 1024;
  short8 a0n0 = *(const short8*)(Ar0 + row * 64 + kg * 8);
  short8 a1n0 = *(const short8*)(Ar0 + row * 64 + 32 + kg * 8);
  short8 a0n1 = *(const short8*)(Ar1 + row * 64 + kg * 8);
  short8 a1n1 = *(const short8*)(Ar1 + row * 64 + 32 + kg * 8);
#pragma unroll
  for (int sub = 0; sub < 2; ++sub) {
    short8 a0 = sub ? a0n1 : a0n0;
    short8 a1 = sub ? a1n1 : a1n0;
    int sp = sub ? sp1 : sp0;
#pragma unroll
    for (int dc = 0; dc < 4; ++dc) {
      f32x4 acc = {0.f, 0.f, 0.f, 0.f};
      acc = __builtin_amdgcn_mfma_f32_16x16x32_bf16(a0, WF[dc][0], acc, 0, 0, 0);
      acc = __builtin_amdgcn_mfma_f32_16x16x32_bf16(a1, WF[dc][1], acc, 0, 0, 0);
      // acc[r] = A2[s = kg*4+r][d = dc*16+row]
      float psq = acc[0] * acc[0] + acc[1] * acc[1] + acc[2] * acc[2] + acc[3] * acc[3];
      psq += __shfl_xor(psq, 16, 64);
      psq += __shfl_xor(psq, 32, 64);
      float p1 = __shfl(acc[0], lane & 15, 64);
      float p3 = psq * p1;
      int d = dc * 16 + row;
      float qv = Wc[(sp * 3 + 0) * 64 + d] * p1 + Wc[(sp * 3 + 1) * 64 + d] * psq +
                 Wc[(sp * 3 + 2) * 64 + d] * p3;
      if (kg == 0) qs[nl * 2 + sub][d] = qv;
    }
  }
  __syncthreads();
  int t = lane;
  const float* f0 = featsOld + (size_t)base * 64;
  const float* f1 = f0 + 64;
  float sc0 = 0.f, sc1 = 0.f;
#pragma unroll 8
  for (int c = 0; c < 64; ++c) {
    sc0 += f0[c] * Wskip[(c * NE_EL + sp0) * 64 + t];
    sc1 += f1[c] * Wskip[(c * NE_EL + sp1) * 64 + t];
  }
  float nf0 = sc0, nf1 = sc1;
#pragma unroll 8
  for (int d = 0; d < 64; ++d) {
    nf0 += qs[nl * 2 + 0][d] * Wouts[d * 64 + t];
    nf1 += qs[nl * 2 + 1][d] * Wouts[d * 64 + t];
  }
  featsNew[(size_t)base * 64 + t] = nf0;
  featsNew[(size_t)(base + 1) * 64 + t] = nf1;
  int b0 = batch[base], b1 = batch[base + 1];
  float en0 = nf0 * Wro[t * N_HEADS + headArr[b0]];
  float en1 = nf1 * Wro[t * N_HEADS + headArr[b1]];
#pragma unroll
  for (int off = 32; off; off >>= 1) {
    en0 += __shfl_down(en0, off, 64);
    en1 += __shfl_down(en1, off, 64);
  }
  if (t == 0) {
    atomicAdd(&out[b0], en0);
    atomicAdd(&out[b1], en1);
  }
}

extern "C" void kernel_launch(void* const* d_in, const int* in_sizes, int n_in,
                              void* d_out, int out_size, void* d_ws, size_t ws_size,
                              hipStream_t stream) {
  const float* pos = (const float*)d_in[0];
  const float* attrs = (const float*)d_in[1];
  const float* shifts = (const float*)d_in[2];
  const float* ae = (const float*)d_in[3];
  const float* Wemb = (const float*)d_in[4];
  const float* Wup = (const float*)d_in[5];
  const float* w1 = (const float*)d_in[6];
  const float* w2 = (const float*)d_in[7];
  const float* w3 = (const float*)d_in[8];
  const float* Wmix = (const float*)d_in[9];
  const float* Wskip = (const float*)d_in[10];
  const float* Wc = (const float*)d_in[11];
  const float* Wout = (const float*)d_in[12];
  const float* Wro = (const float*)d_in[13];
  const int* ei = (const int*)d_in[14];
  const int* batch = (const int*)d_in[15];
  const int* head = (const int*)d_in[16];
  float* out = (float*)d_out;

  char* p = (char*)d_ws;
  float* Yp = (float*)p;     p += (size_t)N_EDGES * 16 * 4;
  float* radp = (float*)p;   p += (size_t)N_EDGES * 8 * 4;
  float* up = (float*)p;     p += (size_t)N_NODES * 64 * 4;
  float* upe = (float*)p;    p += (size_t)N_EDGES * 64 * 4;
  float* fA = (float*)p;     p += (size_t)N_NODES * 64 * 4;
  float* fB = (float*)p;     p += (size_t)N_NODES * 64 * 4;
  u16* AbufB = (u16*)p;      p += (size_t)N_NODES * 1024 * 2;
  u16* h2 = (u16*)p;         p += (size_t)N_EDGES * 64 * 2;
  u16* W3T = (u16*)p;        p += (size_t)L_LAY * 65536 * 2;
  u16* w2T = (u16*)p;        p += (size_t)L_LAY * 4096 * 2;
  u16* WmixF = (u16*)p;      p += (size_t)L_LAY * 4096 * 2;
  int* species = (int*)p;    p += (size_t)N_NODES * 4;
  int* deg = (int*)p;        p += (size_t)N_NODES * 4;
  int* rowptr = (int*)p;     p += (size_t)(N_NODES + 4) * 4;
  int* woff = (int*)p;       p += (size_t)N_NODES * 4;
  int* rank = (int*)p;       p += (size_t)N_EDGES * 4;
  int* sndp = (int*)p;       p += (size_t)N_EDGES * 4;
  if ((size_t)(p - (char*)d_ws) > ws_size) return;

  k_init0<<<(N_NODES + 255) / 256, 256, 0, stream>>>(out, deg);
  k_node_init<<<(N_NODES + 255) / 256, 256, 0, stream>>>(attrs, ae, batch, head, species, out);
  k_embed<<<(N_NODES * C_CH + 255) / 256, 256, 0, stream>>>(species, Wemb, fA);
  k_hist<<<(N_EDGES + 255) / 256, 256, 0, stream>>>(ei, deg);
  k_scan<<<1, 1024, 0, stream>>>(deg, rowptr, woff);
  k_permute<<<(N_EDGES + 255) / 256, 256, 0, stream>>>(ei, woff, rank, sndp);
  k_geom<<<(N_EDGES + 255) / 256, 256, 0, stream>>>(pos, shifts, ei, rank, Yp, radp);
  k_prep<<<(L_LAY * 65536 + 2 * L_LAY * 4096 + 255) / 256, 256, 0, stream>>>(w3, w2, Wmix, W3T,
                                                                             w2T, WmixF);

  const float* fOld = fA;
  float* fNew = fB;
  for (int l = 0; l < L_LAY; ++l) {
    k_edge_mlp<<<N_EDGES / 16, 64, 0, stream>>>(radp, w1 + l * NB_R * HID_D, w2T + l * 4096, h2);
    k_up<<<512, 256, 0, stream>>>(fOld, Wup + l * C_CH * C_CH, up);
    k_upe<<<2048, 256, 0, stream>>>(up, sndp, upe);
    k_gather<<<N_NODES / 4, 64, 0, stream>>>(h2, W3T + l * 65536, upe, Yp, rowptr, AbufB);
    k_node_update<<<N_NODES / 8, 256, 0, stream>>>(
        AbufB, fOld, fNew, WmixF + l * 4096, Wskip + l * C_CH * NE_EL * C_CH,
        Wc + l * NE_EL * 3 * C_CH, Wout + l * C_CH * C_CH, Wro + l * C_CH * N_HEADS,
        species, batch, head, out);
    const float* tmp = fNew;
    fNew = (float*)fOld;
    fOld = tmp;
  }
}

// Round 7
// 450.451 us; speedup vs baseline: 2.5899x; 1.1214x over previous
//
#include <hip/hip_runtime.h>

typedef unsigned short u16;
typedef unsigned int u32;
typedef __attribute__((ext_vector_type(8))) short short8;
typedef __attribute__((ext_vector_type(4))) float f32x4;

#define N_NODES 10000
#define N_EDGES 100000
#define C_CH 64
#define S_SPH 16
#define NB_R 8
#define HID_D 64
#define NE_EL 10
#define G_GR 64
#define L_LAY 2
#define N_HEADS 1
#define RCUT 5.0f
#define INV_AVG (1.0f/16.0f)

__device__ __forceinline__ u16 f2bf(float f) {
  u32 u = __float_as_uint(f);
  u32 r = (u + 0x7FFFu + ((u >> 16) & 1u)) >> 16;
  return (u16)r;
}

__global__ void k_init0(float* __restrict__ out, int* __restrict__ deg) {
  int i = blockIdx.x * 256 + threadIdx.x;
  if (i < G_GR) out[i] = 0.0f;
  if (i < N_NODES) deg[i] = 0;
}

__global__ void k_node_init(const float* __restrict__ attrs, const float* __restrict__ ae,
                            const int* __restrict__ batch, const int* __restrict__ head,
                            int* __restrict__ species, float* __restrict__ out) {
  int n = blockIdx.x * 256 + threadIdx.x;
  if (n >= N_NODES) return;
  int sp = 0;
#pragma unroll
  for (int e = 0; e < NE_EL; ++e)
    if (attrs[n * NE_EL + e] > 0.5f) sp = e;
  species[n] = sp;
  int b = batch[n];
  int h = head[b];
  atomicAdd(&out[b], ae[h * NE_EL + sp]);
}

__global__ void k_embed(const int* __restrict__ species, const float* __restrict__ Wemb,
                        float* __restrict__ feats) {
  int idx = blockIdx.x * 256 + threadIdx.x;
  if (idx >= N_NODES * C_CH) return;
  feats[idx] = Wemb[species[idx >> 6] * C_CH + (idx & 63)];
}

__global__ void k_hist(const int* __restrict__ ei, int* __restrict__ deg) {
  int e = blockIdx.x * 256 + threadIdx.x;
  if (e >= N_EDGES) return;
  atomicAdd(&deg[ei[N_EDGES + e]], 1);
}

__global__ void __launch_bounds__(1024) k_scan(const int* __restrict__ deg,
                                               int* __restrict__ rowptr,
                                               int* __restrict__ woff) {
  __shared__ int wsum[16];
  __shared__ int carry_s;
  int tid = threadIdx.x;
  int lane = tid & 63, w = tid >> 6;
  if (tid == 0) carry_s = 0;
  __syncthreads();
  for (int base = 0; base < N_NODES; base += 1024) {
    int i = base + tid;
    int v = (i < N_NODES) ? deg[i] : 0;
    int orig = v;
#pragma unroll
    for (int off = 1; off < 64; off <<= 1) {
      int n = __shfl_up(v, off, 64);
      if (lane >= off) v += n;
    }
    if (lane == 63) wsum[w] = v;
    __syncthreads();
    if (w == 0 && lane < 16) {
      int x = wsum[lane];
#pragma unroll
      for (int off = 1; off < 16; off <<= 1) {
        int n = __shfl_up(x, off, 16);
        if (lane >= off) x += n;
      }
      wsum[lane] = x;
    }
    __syncthreads();
    int waveoff = (w > 0) ? wsum[w - 1] : 0;
    int carry = carry_s;
    int excl = carry + waveoff + v - orig;
    if (i < N_NODES) {
      rowptr[i] = excl;
      woff[i] = excl;
    }
    int tot = wsum[15];
    __syncthreads();
    if (tid == 0) carry_s = carry + tot;
    __syncthreads();
  }
  if (tid == 0) rowptr[N_NODES] = carry_s;
}

__global__ void k_permute(const int* __restrict__ ei, int* __restrict__ woff,
                          int* __restrict__ rank, int* __restrict__ sndp) {
  int e = blockIdx.x * 256 + threadIdx.x;
  if (e >= N_EDGES) return;
  int rdst = ei[N_EDGES + e];
  int pos = atomicAdd(&woff[rdst], 1);
  rank[e] = pos;
  sndp[pos] = ei[e];
}

__global__ void k_geom(const float* __restrict__ pos, const float* __restrict__ shifts,
                       const int* __restrict__ ei, const int* __restrict__ rank,
                       float* __restrict__ Yp, float* __restrict__ radp) {
  int e = blockIdx.x * 256 + threadIdx.x;
  if (e >= N_EDGES) return;
  int s = ei[e], r = ei[N_EDGES + e];
  float dx = pos[r * 3 + 0] - pos[s * 3 + 0] + shifts[e * 3 + 0];
  float dy = pos[r * 3 + 1] - pos[s * 3 + 1] + shifts[e * 3 + 1];
  float dz = pos[r * 3 + 2] - pos[s * 3 + 2] + shifts[e * 3 + 2];
  float rr = sqrtf(dx * dx + dy * dy + dz * dz);
  rr = fmaxf(rr, 1e-12f);
  float inv = 1.0f / rr;
  float x = dx * inv, y = dy * inv, z = dz * inv;
  float xx = x * x, yy = y * y, zz = z * z;
  const float s3 = 1.73205080757f, s5 = 2.2360679775f, s15 = 3.87298334621f;
  const float c1 = 2.09165006634f, c2 = 10.2469507659f, c3 = 1.62018517461f;
  const float c4 = 1.32287565553f, c5 = 5.12347538298f;
  int rk = rank[e];
  float4* Yo = (float4*)(Yp + (size_t)rk * 16);
  Yo[0] = make_float4(1.0f, s3 * x, s3 * y, s3 * z);
  Yo[1] = make_float4(s15 * x * y, s15 * y * z, 0.5f * s5 * (3.0f * zz - 1.0f), s15 * x * z);
  Yo[2] = make_float4(0.5f * s15 * (xx - yy), c1 * y * (3.0f * xx - yy), c2 * x * y * z,
                      c3 * y * (5.0f * zz - 1.0f));
  Yo[3] = make_float4(c4 * z * (5.0f * zz - 3.0f), c3 * x * (5.0f * zz - 1.0f),
                      c5 * z * (xx - yy), c1 * x * (xx - 3.0f * yy));
  float t = rr * (1.0f / RCUT);
  float t2 = t * t;
  float t6 = t2 * t2 * t2;
  float fcut = 1.0f - 28.0f * t6 + 48.0f * t6 * t - 21.0f * t6 * t2;
  if (rr >= RCUT) fcut = 0.0f;
  float pref = 0.63245553203f * inv * fcut;
  float arg = 3.14159265359f * rr * (1.0f / RCUT);
  float sa, ca;
  __sincosf(arg, &sa, &ca);
  float twoc = 2.0f * ca;
  float sprev = 0.0f, scur = sa;
  float rv[8];
#pragma unroll
  for (int n = 0; n < 8; ++n) {
    rv[n] = pref * scur;
    float snext = twoc * scur - sprev;
    sprev = scur;
    scur = snext;
  }
  float4* Ro = (float4*)(radp + (size_t)rk * 8);
  Ro[0] = make_float4(rv[0], rv[1], rv[2], rv[3]);
  Ro[1] = make_float4(rv[4], rv[5], rv[6], rv[7]);
}

// W3T[l][s][c][k] bf16; w2T[l][t][j] bf16; WmixF = Wmix packed as MFMA B-fragments
__global__ void k_prep(const float* __restrict__ w3, const float* __restrict__ w2,
                       const float* __restrict__ wmix, u16* __restrict__ w3t,
                       u16* __restrict__ w2t, u16* __restrict__ wmixf) {
  int idx = blockIdx.x * 256 + threadIdx.x;
  if (idx < L_LAY * 65536) {
    int l = idx >> 16;
    int r = idx & 65535;
    int k = r & 63;
    int c = (r >> 6) & 63;
    int s = r >> 12;
    w3t[idx] = f2bf(w3[(l * 64 + k) * 1024 + c * 16 + s]);
  } else if (idx < L_LAY * 65536 + L_LAY * 4096) {
    int i = idx - L_LAY * 65536;
    int l = i >> 12;
    int r = i & 4095;
    int t = r >> 6;
    int j = r & 63;
    w2t[l * 4096 + t * 64 + j] = f2bf(w2[(l * 64 + j) * 64 + t]);
  } else if (idx < L_LAY * 65536 + 2 * L_LAY * 4096) {
    int i = idx - L_LAY * 65536 - L_LAY * 4096;
    int l = i >> 12;
    int r = i & 4095;
    int j = r & 7;
    int col = (r >> 3) & 15;
    int kg = (r >> 7) & 3;
    int hf = (r >> 9) & 1;
    int dc = (r >> 10) & 3;
    int c = hf * 32 + kg * 8 + j;
    int d = dc * 16 + col;
    wmixf[l * 4096 + r] = f2bf(wmix[(l * 64 + c) * 64 + d]);
  }
}

// edge MLP, MFMA layer-2: 1 wave = 16 edges. h1 staged bf16 in LDS, XOR-swizzled.
__global__ void __launch_bounds__(64) k_edge_mlp(const float* __restrict__ radp,
                                                 const float* __restrict__ w1,
                                                 const u16* __restrict__ w2T,
                                                 u16* __restrict__ h2) {
  __shared__ float w1s[NB_R * HID_D];
  __shared__ __align__(16) u16 h1b[16 * 64];
  int lane = threadIdx.x;
  for (int i = lane; i < NB_R * HID_D; i += 64) w1s[i] = w1[i];
  int er = lane & 15, jg = lane >> 4;
  int eb = blockIdx.x * 16;
  int e = eb + er;
  float4 ra = *(const float4*)(radp + (size_t)e * 8);
  float4 rb = *(const float4*)(radp + (size_t)e * 8 + 4);
  float rv[8] = {ra.x, ra.y, ra.z, ra.w, rb.x, rb.y, rb.z, rb.w};
  u32* hb = (u32*)h1b;
#pragma unroll
  for (int jj = 0; jj < 16; jj += 2) {
    float p0 = 0.f, p1 = 0.f;
#pragma unroll
    for (int k = 0; k < 8; ++k) {
      p0 += rv[k] * w1s[k * 64 + jg * 16 + jj];
      p1 += rv[k] * w1s[k * 64 + jg * 16 + jj + 1];
    }
    p0 = p0 / (1.f + __expf(-p0));
    p1 = p1 / (1.f + __expf(-p1));
    u32 packed = (u32)f2bf(p0) | ((u32)f2bf(p1) << 16);
    int d = jg * 8 + (jj >> 1);
    hb[er * 32 + (d ^ ((er & 7) << 2))] = packed;
  }
  int row = er, kg = jg, col = er;
  const u32* hbr = (const u32*)h1b;
  short8 a0 = *(const short8*)&hbr[row * 32 + ((kg * 4) ^ ((row & 7) << 2))];
  short8 a1 = *(const short8*)&hbr[row * 32 + ((16 + kg * 4) ^ ((row & 7) << 2))];
#pragma unroll
  for (int ch = 0; ch < 4; ++ch) {
    const u16* wp = w2T + (ch * 16 + col) * 64 + kg * 8;
    short8 b0 = *(const short8*)wp;
    short8 b1 = *(const short8*)(wp + 32);
    f32x4 acc = {0.f, 0.f, 0.f, 0.f};
    acc = __builtin_amdgcn_mfma_f32_16x16x32_bf16(a0, b0, acc, 0, 0, 0);
    acc = __builtin_amdgcn_mfma_f32_16x16x32_bf16(a1, b1, acc, 0, 0, 0);
#pragma unroll
    for (int rr = 0; rr < 4; ++rr) {
      float v = acc[rr];
      v = v / (1.f + __expf(-v));
      h2[(size_t)(eb + kg * 4 + rr) * 64 + ch * 16 + col] = f2bf(v);
    }
  }
}

// up = feats @ W_up * INV_AVG
__global__ void __launch_bounds__(256) k_up(const float* __restrict__ feats,
                                            const float* __restrict__ Wup,
                                            float* __restrict__ up) {
  __shared__ float ws[C_CH * C_CH];
  __shared__ float fs[4][C_CH];
  int tid = threadIdx.x;
  for (int i = tid; i < C_CH * C_CH; i += 256) ws[i] = Wup[i];
  __syncthreads();
  int slot = tid >> 6, t = tid & 63;
  for (int nb = blockIdx.x * 4; nb < N_NODES; nb += gridDim.x * 4) {
    int n = nb + slot;
    fs[slot][t] = feats[n * C_CH + t];
    float acc = 0.0f;
#pragma unroll
    for (int j = 0; j < C_CH; ++j) acc += fs[slot][j] * ws[j * C_CH + t];
    up[n * C_CH + t] = acc * INV_AVG;
  }
}

// upe[pos][c] = up[sndp[pos]][c]
__global__ void __launch_bounds__(256) k_upe(const float* __restrict__ up,
                                             const int* __restrict__ sndp,
                                             float* __restrict__ upe) {
  int tid = threadIdx.x;
  int slot = tid >> 6, t = tid & 63;
  for (int pb = blockIdx.x * 4; pb < N_EDGES; pb += gridDim.x * 4) {
    int pos = pb + slot;
    upe[(size_t)pos * 64 + t] = up[(size_t)sndp[pos] * 64 + t];
  }
}

// Fused gather + node update: 1 wave per block, 4 nodes.
// Phase 1: edge reduction (MFMA tp_w, Areg accumulators) -> A staged bf16 in LDS.
// Phase 2: mix A@Wmix via MFMA (fragments from LDS), poly p1/p2/p3 -> q in LDS.
// Phase 3: skip + Wout + readout energy; feats written, energy atomics.
__global__ void __launch_bounds__(64) k_gather_fused(
    const u16* __restrict__ h2, const u16* __restrict__ W3T, const float* __restrict__ upe,
    const float* __restrict__ Yp, const int* __restrict__ rowptr,
    const u16* __restrict__ WmixF, const float* __restrict__ featsOld,
    float* __restrict__ featsNew, const float* __restrict__ Wskip,
    const float* __restrict__ Wc, const float* __restrict__ WoutG,
    const float* __restrict__ Wro, const int* __restrict__ species,
    const int* __restrict__ batch, const int* __restrict__ headArr,
    float* __restrict__ out) {
  __shared__ __align__(16) float Yt[16][20];
  __shared__ __align__(16) u16 Asub[4][16][72];  // bf16 A[node][s][c], pitch 72
  __shared__ float qs[4][64];
  __shared__ float fsub[4][64];
  int lane = threadIdx.x;
  int row = lane & 15, kg = lane >> 4;
  int col = row;
  int nb = blockIdx.x * 4;
  // stage feats for skip (early, hides latency under phase 1)
#pragma unroll
  for (int k = 0; k < 4; ++k) fsub[k][lane] = featsOld[(size_t)(nb + k) * 64 + lane];
  int rp0 = rowptr[nb], rp1 = rowptr[nb + 1], rp2 = rowptr[nb + 2], rp3 = rowptr[nb + 3],
      rp4 = rowptr[nb + 4];
  int d0 = rp1 - rp0, d1 = rp2 - rp1, d2 = rp3 - rp2, d3 = rp4 - rp3;
  int rmax = max(max((d0 + 3) >> 2, (d1 + 3) >> 2), max((d2 + 3) >> 2, (d3 + 3) >> 2));
  rmax = max(rmax, 1);
  int nr = row >> 2;
  int baseA = nr == 0 ? rp0 : nr == 1 ? rp1 : nr == 2 ? rp2 : rp3;
  int degA = nr == 0 ? d0 : nr == 1 ? d1 : nr == 2 ? d2 : d3;
  int baseR = kg == 0 ? rp0 : kg == 1 ? rp1 : kg == 2 ? rp2 : rp3;
  int degR = kg == 0 ? d0 : kg == 1 ? d1 : kg == 2 ? d2 : d3;

  // ---- phase 1: edge reduction ----
#pragma unroll 1
  for (int cg = 0; cg < 4; ++cg) {
#pragma unroll 1
    for (int hf = 0; hf < 2; ++hf) {
      short8 B0[8], B1[8];
#pragma unroll
      for (int ss = 0; ss < 8; ++ss) {
        int s = hf * 8 + ss;
        const u16* wp = W3T + (((s * 64 + cg * 16 + col) << 6) + kg * 8);
        B0[ss] = *(const short8*)wp;
        B1[ss] = *(const short8*)(wp + 32);
      }
      float Areg[8];
#pragma unroll
      for (int ss = 0; ss < 8; ++ss) Areg[ss] = 0.f;
#pragma unroll 1
      for (int r = 0; r < rmax; ++r) {
        int sl = r * 4 + (row & 3);
        short8 a0 = {0, 0, 0, 0, 0, 0, 0, 0};
        short8 a1 = {0, 0, 0, 0, 0, 0, 0, 0};
        float4 yq = make_float4(0.f, 0.f, 0.f, 0.f);
        if (sl < degA) {
          int eA = baseA + sl;
          a0 = *(const short8*)(h2 + (size_t)eA * 64 + kg * 8);
          a1 = *(const short8*)(h2 + (size_t)eA * 64 + 32 + kg * 8);
          yq = *(const float4*)(Yp + (size_t)eA * 16 + kg * 4);
        }
        Yt[kg * 4 + 0][row] = yq.x;
        Yt[kg * 4 + 1][row] = yq.y;
        Yt[kg * 4 + 2][row] = yq.z;
        Yt[kg * 4 + 3][row] = yq.w;
        float upv[4];
#pragma unroll
        for (int q = 0; q < 4; ++q) {
          int slq = r * 4 + q;
          int pos = (slq < degR) ? (baseR + slq) : 0;
          float u = upe[(size_t)pos * 64 + cg * 16 + col];
          upv[q] = (slq < degR) ? u : 0.f;
        }
#pragma unroll
        for (int ss = 0; ss < 8; ++ss) {
          f32x4 acc = {0.f, 0.f, 0.f, 0.f};
          acc = __builtin_amdgcn_mfma_f32_16x16x32_bf16(a0, B0[ss], acc, 0, 0, 0);
          acc = __builtin_amdgcn_mfma_f32_16x16x32_bf16(a1, B1[ss], acc, 0, 0, 0);
          float4 yv = *(const float4*)&Yt[hf * 8 + ss][kg * 4];
          Areg[ss] += acc[0] * yv.x * upv[0] + acc[1] * yv.y * upv[1] + acc[2] * yv.z * upv[2] +
                      acc[3] * yv.w * upv[3];
        }
      }
      // stage to LDS: Asub[node=kg][s=hf*8+ss][c=cg*16+col]
#pragma unroll
      for (int ss = 0; ss < 8; ++ss) Asub[kg][hf * 8 + ss][cg * 16 + col] = f2bf(Areg[ss]);
    }
  }
  __syncthreads();

  // ---- phase 2: mix + poly -> q ----
  short8 WF[4][2];
#pragma unroll
  for (int dc = 0; dc < 4; ++dc)
#pragma unroll
    for (int hf = 0; hf < 2; ++hf)
      WF[dc][hf] = *(const short8*)(WmixF + (size_t)(dc * 1024 + hf * 512 + kg * 128 + row * 8));
  int spArr[4];
#pragma unroll
  for (int k = 0; k < 4; ++k) spArr[k] = species[nb + k];
#pragma unroll 1
  for (int i = 0; i < 4; ++i) {
    short8 a0 = *(const short8*)&Asub[i][row][kg * 8];
    short8 a1 = *(const short8*)&Asub[i][row][32 + kg * 8];
    int sp = spArr[i];
#pragma unroll
    for (int dc = 0; dc < 4; ++dc) {
      f32x4 acc = {0.f, 0.f, 0.f, 0.f};
      acc = __builtin_amdgcn_mfma_f32_16x16x32_bf16(a0, WF[dc][0], acc, 0, 0, 0);
      acc = __builtin_amdgcn_mfma_f32_16x16x32_bf16(a1, WF[dc][1], acc, 0, 0, 0);
      // acc[r] = A2[s=kg*4+r][d=dc*16+row]
      float psq = acc[0] * acc[0] + acc[1] * acc[1] + acc[2] * acc[2] + acc[3] * acc[3];
      psq += __shfl_xor(psq, 16, 64);
      psq += __shfl_xor(psq, 32, 64);
      float p1 = __shfl(acc[0], lane & 15, 64);
      float p3 = psq * p1;
      int d = dc * 16 + row;
      float qv = Wc[(sp * 3 + 0) * 64 + d] * p1 + Wc[(sp * 3 + 1) * 64 + d] * psq +
                 Wc[(sp * 3 + 2) * 64 + d] * p3;
      if (kg == 0) qs[i][d] = qv;
    }
  }
  __syncthreads();

  // ---- phase 3: skip + Wout + energy ----
  int t = lane;
  float en[4];
  int bArr[4];
#pragma unroll 1
  for (int i = 0; i < 4; ++i) {
    int sp = spArr[i];
    float sc = 0.f;
#pragma unroll 8
    for (int c = 0; c < 64; ++c) sc += fsub[i][c] * Wskip[(c * NE_EL + sp) * 64 + t];
    float v = sc;
#pragma unroll 8
    for (int d = 0; d < 64; ++d) v += qs[i][d] * WoutG[d * 64 + t];
    featsNew[(size_t)(nb + i) * 64 + t] = v;
    int b = batch[nb + i];
    bArr[i] = b;
    en[i] = v * Wro[t * N_HEADS + headArr[b]];
  }
#pragma unroll
  for (int off = 32; off; off >>= 1) {
#pragma unroll
    for (int i = 0; i < 4; ++i) en[i] += __shfl_down(en[i], off, 64);
  }
  if (lane == 0) {
#pragma unroll
    for (int i = 0; i < 4; ++i) atomicAdd(&out[bArr[i]], en[i]);
  }
}

extern "C" void kernel_launch(void* const* d_in, const int* in_sizes, int n_in,
                              void* d_out, int out_size, void* d_ws, size_t ws_size,
                              hipStream_t stream) {
  const float* pos = (const float*)d_in[0];
  const float* attrs = (const float*)d_in[1];
  const float* shifts = (const float*)d_in[2];
  const float* ae = (const float*)d_in[3];
  const float* Wemb = (const float*)d_in[4];
  const float* Wup = (const float*)d_in[5];
  const float* w1 = (const float*)d_in[6];
  const float* w2 = (const float*)d_in[7];
  const float* w3 = (const float*)d_in[8];
  const float* Wmix = (const float*)d_in[9];
  const float* Wskip = (const float*)d_in[10];
  const float* Wc = (const float*)d_in[11];
  const float* Wout = (const float*)d_in[12];
  const float* Wro = (const float*)d_in[13];
  const int* ei = (const int*)d_in[14];
  const int* batch = (const int*)d_in[15];
  const int* head = (const int*)d_in[16];
  float* out = (float*)d_out;

  char* p = (char*)d_ws;
  float* Yp = (float*)p;     p += (size_t)N_EDGES * 16 * 4;
  float* radp = (float*)p;   p += (size_t)N_EDGES * 8 * 4;
  float* up = (float*)p;     p += (size_t)N_NODES * 64 * 4;
  float* upe = (float*)p;    p += (size_t)N_EDGES * 64 * 4;
  float* fA = (float*)p;     p += (size_t)N_NODES * 64 * 4;
  float* fB = (float*)p;     p += (size_t)N_NODES * 64 * 4;
  u16* h2 = (u16*)p;         p += (size_t)N_EDGES * 64 * 2;
  u16* W3T = (u16*)p;        p += (size_t)L_LAY * 65536 * 2;
  u16* w2T = (u16*)p;        p += (size_t)L_LAY * 4096 * 2;
  u16* WmixF = (u16*)p;      p += (size_t)L_LAY * 4096 * 2;
  int* species = (int*)p;    p += (size_t)N_NODES * 4;
  int* deg = (int*)p;        p += (size_t)N_NODES * 4;
  int* rowptr = (int*)p;     p += (size_t)(N_NODES + 4) * 4;
  int* woff = (int*)p;       p += (size_t)N_NODES * 4;
  int* rank = (int*)p;       p += (size_t)N_EDGES * 4;
  int* sndp = (int*)p;       p += (size_t)N_EDGES * 4;
  if ((size_t)(p - (char*)d_ws) > ws_size) return;

  k_init0<<<(N_NODES + 255) / 256, 256, 0, stream>>>(out, deg);
  k_node_init<<<(N_NODES + 255) / 256, 256, 0, stream>>>(attrs, ae, batch, head, species, out);
  k_embed<<<(N_NODES * C_CH + 255) / 256, 256, 0, stream>>>(species, Wemb, fA);
  k_hist<<<(N_EDGES + 255) / 256, 256, 0, stream>>>(ei, deg);
  k_scan<<<1, 1024, 0, stream>>>(deg, rowptr, woff);
  k_permute<<<(N_EDGES + 255) / 256, 256, 0, stream>>>(ei, woff, rank, sndp);
  k_geom<<<(N_EDGES + 255) / 256, 256, 0, stream>>>(pos, shifts, ei, rank, Yp, radp);
  k_prep<<<(L_LAY * 65536 + 2 * L_LAY * 4096 + 255) / 256, 256, 0, stream>>>(w3, w2, Wmix, W3T,
                                                                             w2T, WmixF);

  const float* fOld = fA;
  float* fNew = fB;
  for (int l = 0; l < L_LAY; ++l) {
    k_edge_mlp<<<N_EDGES / 16, 64, 0, stream>>>(radp, w1 + l * NB_R * HID_D, w2T + l * 4096, h2);
    k_up<<<512, 256, 0, stream>>>(fOld, Wup + l * C_CH * C_CH, up);
    k_upe<<<2048, 256, 0, stream>>>(up, sndp, upe);
    k_gather_fused<<<N_NODES / 4, 64, 0, stream>>>(
        h2, W3T + l * 65536, upe, Yp, rowptr, WmixF + l * 4096, fOld, fNew,
        Wskip + l * C_CH * NE_EL * C_CH, Wc + l * NE_EL * 3 * C_CH, Wout + l * C_CH * C_CH,
        Wro + l * C_CH * N_HEADS, species, batch, head, out);
    const float* tmp = fNew;
    fNew = (float*)fOld;
    fOld = tmp;
  }
}